// Round 6
// baseline (8093.534 us; speedup 1.0000x reference)
//
#include <hip/hip_runtime.h>
#include <math.h>

#define NTOK 201
#define EDIM 128
#define LDX  132
#define NHEAD 4
#define HD   32
#define NLAY 6
#define NEXP 5
#define FFD  256
#define NCAT 53
#define NNUM 47
#define NENG 100
#define NEMB 1352
#define SEQL 51
#define NB   512
#define LN_EPS 1e-5f
#define SCALE 0.17677669529663687f

typedef __attribute__((ext_vector_type(8))) short bfrag;           // 8 bf16
typedef __attribute__((ext_vector_type(4))) float f32x4;           // mfma acc
typedef __attribute__((ext_vector_type(8))) unsigned short u16x8;
typedef __attribute__((ext_vector_type(4))) unsigned short u16x4;

__device__ __forceinline__ float bf2f(unsigned short u){ return __uint_as_float(((unsigned)u)<<16); }
__device__ __forceinline__ unsigned short f2bf(float f){
  unsigned u = __float_as_uint(f);
  return (unsigned short)((u + 0x7FFFu + ((u>>16)&1u)) >> 16);
}

// ---------------- workspace layout (bytes) ----------------
#define OFF_WQH  0u            // Wqkv hi  [6][384][128] bf16 (Q rows pre-scaled)
#define OFF_WQL  589824u       // Wqkv lo
#define OFF_BQ   1179648u      // bqkv f32 [6][384]
#define OFF_WOH  1188864u      // Wo hi [6][128][128] bf16 ([j][d])
#define OFF_WOL  1385472u
#define OFF_W1H  1582080u      // W1T hi [6][5][256][128] bf16
#define OFF_W1L  3548160u
#define OFF_W2H  5514240u      // W2T hi [6][5][128][256] bf16
#define OFF_W2L  7480320u

// ---------------- prep kernels ----------------
__global__ void prep_qkv_bf(const float* __restrict__ Wqkv, const float* __restrict__ bqkv,
                            unsigned short* __restrict__ Wqh, unsigned short* __restrict__ Wql,
                            float* __restrict__ bq){
  int bid = blockIdx.x; int n = bid % 384; int e = threadIdx.x;
  float sc = (n < 128) ? SCALE : 1.0f;
  float w = Wqkv[(size_t)bid*128 + e] * sc;
  unsigned short h = f2bf(w), l = f2bf(w - bf2f(h));
  Wqh[(size_t)bid*128 + e] = h; Wql[(size_t)bid*128 + e] = l;
  if (e == 0) bq[bid] = bqkv[bid] * sc;
}

__global__ void prep_wo_bf(const float* __restrict__ Wo,
                           unsigned short* __restrict__ Woh, unsigned short* __restrict__ Wol){
  int idx = blockIdx.x*blockDim.x + threadIdx.x;
  if (idx >= 6*128*128) return;
  float w = Wo[idx];
  unsigned short h = f2bf(w), l = f2bf(w - bf2f(h));
  Woh[idx] = h; Wol[idx] = l;
}

__global__ void prep_moe(const float* __restrict__ W1, const float* __restrict__ W2,
                         unsigned short* __restrict__ W1h, unsigned short* __restrict__ W1l,
                         unsigned short* __restrict__ W2h, unsigned short* __restrict__ W2l){
  const int Ntot = 6*5*128*256;
  for (int idx = blockIdx.x*blockDim.x + threadIdx.x; idx < Ntot; idx += gridDim.x*blockDim.x){
    int lx = idx / 32768; int rem = idx & 32767; int e = rem >> 8; int f = rem & 255;
    float w = W1[idx];
    unsigned short h = f2bf(w); unsigned short l = f2bf(w - bf2f(h));
    size_t o1 = (size_t)(lx*256+f)*128 + e;
    W1h[o1] = h; W1l[o1] = l;
    int f2 = (idx >> 7) & 255; int e2 = idx & 127;
    float w2 = W2[idx];
    unsigned short h2 = f2bf(w2); unsigned short l2 = f2bf(w2 - bf2f(h2));
    size_t o2 = (size_t)(lx*128+e2)*256 + f2;
    W2h[o2] = h2; W2l[o2] = l2;
  }
}

// ---------------- main kernel ----------------
struct Params {
  const int*   x_cat;
  const float* x_num;
  const float* x_eng;
  const float* emb;
  const float* emb_bias;
  const float* emb_eng;
  const float* emb_bias_eng;
  const float* ln0w; const float* ln0b;
  const float* ln1w; const float* ln1b;
  const float* ln2w; const float* ln2b;
  const float* bo;
  const float* Wg;   const float* bg;
  const float* b1;   const float* b2;
  const unsigned short* Wqh; const unsigned short* Wql; const float* bq;
  const unsigned short* Woh; const unsigned short* Wol;
  const unsigned short* W1h; const unsigned short* W1l;
  const unsigned short* W2h; const unsigned short* W2l;
  float* out;
};

__device__ __forceinline__ void ln_stats(const float* xs, float* s_m, float* s_r, int tid){
  if (tid < NTOK){
    const float* row = xs + tid*LDX;
    float s0=0,s1=0,s2=0,s3=0;
    for (int e=0;e<EDIM;e+=4){ s0+=row[e]; s1+=row[e+1]; s2+=row[e+2]; s3+=row[e+3]; }
    float m = (s0+s1+s2+s3)*(1.0f/EDIM);
    float v0=0,v1=0,v2=0,v3=0;
    for (int e=0;e<EDIM;e+=4){
      float d0=row[e]-m,d1=row[e+1]-m,d2=row[e+2]-m,d3=row[e+3]-m;
      v0+=d0*d0; v1+=d1*d1; v2+=d2*d2; v3+=d3*d3;
    }
    s_m[tid]=m; s_r[tid]=1.0f/sqrtf((v0+v1+v2+v3)*(1.0f/EDIM)+LN_EPS);
  }
}

// 1024-thread staging of a 32-row LN'd tile, hi/lo bf16, 4 elems/thread
__device__ __forceinline__ void stage_ht(const float* xs, const float* s_m, const float* s_r,
                                         unsigned short* HTh, unsigned short* HTl,
                                         const float* lw, const float* lb, int t0, int tid){
  int row = tid >> 5;            // 0..31
  int c4  = (tid & 31) << 2;     // 0..124
  int t = t0 + row;
  u16x4 hu = (u16x4){0,0,0,0}, lu = (u16x4){0,0,0,0};
  if (t < NTOK){
    float m = s_m[t], r = s_r[t];
    float4 a  = *(const float4*)(&xs[t*LDX + c4]);
    float4 w  = *(const float4*)(lw + c4);
    float4 bb = *(const float4*)(lb + c4);
    float v0 = (a.x-m)*r*w.x + bb.x;
    float v1 = (a.y-m)*r*w.y + bb.y;
    float v2 = (a.z-m)*r*w.z + bb.z;
    float v3 = (a.w-m)*r*w.w + bb.w;
    unsigned short h0=f2bf(v0), h1=f2bf(v1), h2=f2bf(v2), h3=f2bf(v3);
    hu = (u16x4){h0,h1,h2,h3};
    lu = (u16x4){f2bf(v0-bf2f(h0)), f2bf(v1-bf2f(h1)), f2bf(v2-bf2f(h2)), f2bf(v3-bf2f(h3))};
  }
  *(u16x4*)(HTh + row*136 + c4) = hu;
  *(u16x4*)(HTl + row*136 + c4) = lu;
}

__global__ __launch_bounds__(1024, 4) void fam_fwd(Params p){
  __shared__ float xs[NTOK*LDX];          // 106,128 B
  __shared__ float s_m[NTOK], s_r[NTOK];  // 1,608 B
  __shared__ __align__(16) char scb[55296];

  const int b = blockIdx.x, tid = threadIdx.x;
  const int lane = tid & 63, wv = tid >> 6;   // wv 0..15

  // ---- Phase 0: embeddings ----
  {
    const int e = tid & 127, tl = tid >> 7;   // 8 rows per pass
    for (int t = tl; t < NTOK; t += 8){
      float v;
      if (t < NCAT){
        int idx = p.x_cat[b*(SEQL*NCAT) + (SEQL-1)*NCAT + t];
        v = p.emb[idx*EDIM+e] + p.emb_bias[t*EDIM+e];
      } else if (t < NCAT+NNUM){
        int j = t - NCAT;
        float nv = p.x_num[b*(SEQL*NNUM)+(SEQL-1)*NNUM+j];
        v = p.emb[(NEMB-NNUM+1+j)*EDIM+e]*nv + p.emb_bias[(NCAT+j)*EDIM+e];
      } else if (t < NCAT+NNUM+NENG){
        int j = t - (NCAT+NNUM);
        float ev = p.x_eng[b*NENG+j];
        v = p.emb_eng[j*EDIM+e]*ev + p.emb_bias_eng[j*EDIM+e];
      } else v = 0.f;
      xs[t*LDX+e] = v;
    }
  }
  __syncthreads();
  ln_stats(xs, s_m, s_r, tid);
  __syncthreads();
  {
    const int e = tid & 127, tl = tid >> 7;
    for (int t = tl; t < NTOK; t += 8){
      float m = s_m[t], r = s_r[t];
      xs[t*LDX+e] = (xs[t*LDX+e]-m)*r*p.ln0w[e] + p.ln0b[e];
    }
  }
  __syncthreads();

  // ---- attn LDS pointers ----
  unsigned short* Kh  = (unsigned short*)scb;                    // [224][40]
  unsigned short* Vt  = (unsigned short*)(scb + 17920);          // [32][232]
  unsigned short* HTh = (unsigned short*)(scb + 32768);          // [32][136]
  unsigned short* HTl = (unsigned short*)(scb + 32768 + 8704);   // [32][136]
  unsigned short* Sb  = (unsigned short*)(scb + 32768);          // [32][232] (aliases HT)
  unsigned short* Ob  = (unsigned short*)(scb + 32768 + 14848);  // [32][40]
  unsigned short* Qmh = (unsigned short*)(scb + 50176);          // [32][40]
  unsigned short* Qml = (unsigned short*)(scb + 52736);          // [32][40]
  float* red  = (float*)(scb + 52736);                           // [16][33] (aliases Qml)
  float* mrow = (float*)(scb + 52736 + 2112);                    // [32]
  float* dsum = (float*)(scb + 52736 + 2240);                    // [32]
  // ---- moe LDS pointers ----
  unsigned short* Ahi = (unsigned short*)scb;
  unsigned short* Alo = (unsigned short*)(scb + 8192);
  unsigned short* Hh  = (unsigned short*)(scb + 16384);
  unsigned short* Hl  = (unsigned short*)(scb + 32768);
  float*          gateb = (float*)(scb + 49152);

  for (int li = 0; li < NLAY; ++li){
    const float* ln1w = p.ln1w + li*EDIM;
    const float* ln1b = p.ln1b + li*EDIM;
    const float* ln2w = p.ln2w + li*EDIM;
    const float* ln2b = p.ln2b + li*EDIM;
    const float* bo   = p.bo + li*EDIM;
    const float* Wg   = p.Wg + li*EDIM*NEXP;
    const float* bg   = p.bg + li*NEXP;
    const float* b1g  = p.b1 + li*NEXP*FFD;
    const float* b2g  = p.b2 + li*NEXP*EDIM;

    ln_stats(xs, s_m, s_r, tid);   // ln1
    __syncthreads();

    f32x4 accW[7];                 // Wo-folded attention delta: wave owns (mfw, jfrag=ngw)
#pragma unroll
    for (int mt=0; mt<7; ++mt) accW[mt]=(f32x4){0,0,0,0};

    const int mfw = wv & 1;
    const int ngw = wv >> 1;       // 0..7

    for (int h = 0; h < NHEAD; ++h){
      // ======== pass 1: K and V (waves 0-7 compute; all stage) ========
      bfrag wbh[4], wbl[4]; float bias1 = 0.f;
      if (wv < 8){
        int sel = wv >> 1;
        int nrow = ((sel < 2) ? (128 + h*HD + sel*16) : (256 + h*HD + (sel-2)*16)) + (lane & 15);
        const unsigned short* Bh = p.Wqh + ((size_t)li*384 + nrow)*128 + 8*(lane>>4);
        const unsigned short* Bl = p.Wql + ((size_t)li*384 + nrow)*128 + 8*(lane>>4);
#pragma unroll
        for (int kf=0; kf<4; ++kf){ wbh[kf] = *(const bfrag*)(Bh + kf*32); wbl[kf] = *(const bfrag*)(Bl + kf*32); }
        bias1 = p.bq[li*384 + nrow];
      }

      for (int mt=0; mt<7; ++mt){
        stage_ht(xs, s_m, s_r, HTh, HTl, ln1w, ln1b, mt*32, tid);
        __syncthreads();
        if (wv < 8){
          int sel = wv >> 1, mf1 = wv & 1;
          f32x4 aA = (f32x4){0,0,0,0}, aB = (f32x4){0,0,0,0};
#pragma unroll
          for (int kf=0; kf<4; ++kf){
            bfrag ah = *(const bfrag*)(HTh + (mf1*16 + (lane&15))*136 + kf*32 + 8*(lane>>4));
            bfrag av = *(const bfrag*)(HTl + (mf1*16 + (lane&15))*136 + kf*32 + 8*(lane>>4));
            if (kf & 1){
              aB = __builtin_amdgcn_mfma_f32_16x16x32_bf16(ah, wbh[kf], aB, 0,0,0);
              aB = __builtin_amdgcn_mfma_f32_16x16x32_bf16(ah, wbl[kf], aB, 0,0,0);
              aB = __builtin_amdgcn_mfma_f32_16x16x32_bf16(av, wbh[kf], aB, 0,0,0);
            } else {
              aA = __builtin_amdgcn_mfma_f32_16x16x32_bf16(ah, wbh[kf], aA, 0,0,0);
              aA = __builtin_amdgcn_mfma_f32_16x16x32_bf16(ah, wbl[kf], aA, 0,0,0);
              aA = __builtin_amdgcn_mfma_f32_16x16x32_bf16(av, wbh[kf], aA, 0,0,0);
            }
          }
          f32x4 acc = aA + aB;
          int col = lane & 15;
          if (sel < 2){
            int d = sel*16 + col;
#pragma unroll
            for (int reg=0; reg<4; ++reg){
              int tok = mt*32 + mf1*16 + 4*(lane>>4) + reg;
              Kh[tok*40 + d] = f2bf(acc[reg] + bias1);
            }
          } else {
            int d = (sel-2)*16 + col;
            int tokb = mt*32 + mf1*16 + 4*(lane>>4);
            u16x4 pk;
#pragma unroll
            for (int reg=0; reg<4; ++reg) pk[reg] = f2bf(acc[reg] + bias1);
            *(u16x4*)(Vt + d*232 + tokb) = pk;
          }
        }
        __syncthreads();
      }

      // ======== pass 2 ========
      // Wo B-frag: wave owns j-frag ngw
      bfrag wobh, wobl;
      {
        int j = ngw*16 + (lane&15);
        const unsigned short* wb = p.Woh + ((size_t)li*128 + j)*128 + h*HD + 8*(lane>>4);
        const unsigned short* wl = p.Wol + ((size_t)li*128 + j)*128 + h*HD + 8*(lane>>4);
        wobh = *(const bfrag*)wb; wobl = *(const bfrag*)wl;
      }

#pragma unroll
      for (int mt=0; mt<7; ++mt){
        stage_ht(xs, s_m, s_r, HTh, HTl, ln1w, ln1b, mt*32, tid);
        __syncthreads();

        // Q-GEMM (waves 0-3)
        if (wv < 4){
          int mf2 = wv & 1, nf = wv >> 1;
          int nrow = h*HD + nf*16 + (lane & 15);
          const unsigned short* Bh = p.Wqh + ((size_t)li*384 + nrow)*128 + 8*(lane>>4);
          const unsigned short* Bl = p.Wql + ((size_t)li*384 + nrow)*128 + 8*(lane>>4);
          f32x4 aA = (f32x4){0,0,0,0}, aB = (f32x4){0,0,0,0};
#pragma unroll
          for (int kf=0; kf<4; ++kf){
            bfrag ah = *(const bfrag*)(HTh + (mf2*16 + (lane&15))*136 + kf*32 + 8*(lane>>4));
            bfrag av = *(const bfrag*)(HTl + (mf2*16 + (lane&15))*136 + kf*32 + 8*(lane>>4));
            bfrag bh = *(const bfrag*)(Bh + kf*32);
            bfrag bl = *(const bfrag*)(Bl + kf*32);
            if (kf & 1){
              aB = __builtin_amdgcn_mfma_f32_16x16x32_bf16(ah, bh, aB, 0,0,0);
              aB = __builtin_amdgcn_mfma_f32_16x16x32_bf16(ah, bl, aB, 0,0,0);
              aB = __builtin_amdgcn_mfma_f32_16x16x32_bf16(av, bh, aB, 0,0,0);
            } else {
              aA = __builtin_amdgcn_mfma_f32_16x16x32_bf16(ah, bh, aA, 0,0,0);
              aA = __builtin_amdgcn_mfma_f32_16x16x32_bf16(ah, bl, aA, 0,0,0);
              aA = __builtin_amdgcn_mfma_f32_16x16x32_bf16(av, bh, aA, 0,0,0);
            }
          }
          f32x4 acc = aA + aB;
          float bias = p.bq[li*384 + h*HD + nf*16 + (lane&15)];
          int d = nf*16 + (lane & 15);
#pragma unroll
          for (int reg=0; reg<4; ++reg){
            float v = acc[reg] + bias;
            unsigned short hb = f2bf(v);
            int qrow = mf2*16 + 4*(lane>>4) + reg;
            Qmh[qrow*40 + d] = hb;
            Qml[qrow*40 + d] = f2bf(v - bf2f(hb));
          }
        }
        __syncthreads();

        // scores: all 16 waves; wave covers nf in {ngw, ngw+8}
        {
          bfrag qh = *(const bfrag*)(Qmh + (mfw*16 + (lane&15))*40 + 8*(lane>>4));
          bfrag ql = *(const bfrag*)(Qml + (mfw*16 + (lane&15))*40 + 8*(lane>>4));
#pragma unroll
          for (int rep=0; rep<2; ++rep){
            int nf = ngw + 8*rep;
            if (nf < 14){
              bfrag kb = *(const bfrag*)(Kh + (nf*16 + (lane&15))*40 + 8*(lane>>4));
              f32x4 s = (f32x4){0,0,0,0};
              s = __builtin_amdgcn_mfma_f32_16x16x32_bf16(qh, kb, s, 0,0,0);
              s = __builtin_amdgcn_mfma_f32_16x16x32_bf16(ql, kb, s, 0,0,0);
              int tok = nf*16 + (lane & 15);
#pragma unroll
              for (int reg=0; reg<4; ++reg){
                int q = mfw*16 + 4*(lane>>4) + reg;
                Sb[q*232 + tok] = f2bf(s[reg]);
              }
            }
          }
        }
        __syncthreads();

        // row max: (q = tid&31, kg = tid>>5 in 0..31), 7 cols each
        {
          int q = tid & 31, kg = tid >> 5;
          float pmax = -INFINITY;
#pragma unroll
          for (int j2=0; j2<7; ++j2){
            int k = kg + 32*j2;
            if (k < NTOK) pmax = fmaxf(pmax, bf2f(Sb[q*232 + k]));
          }
          pmax = fmaxf(pmax, __shfl_xor(pmax, 32));
          if (!(tid & 32)) red[wv*33 + q] = pmax;
        }
        __syncthreads();
        if (tid < 32){
          float m = red[tid];
#pragma unroll
          for (int w=1; w<16; ++w) m = fmaxf(m, red[w*33 + tid]);
          mrow[tid] = m;
        }
        __syncthreads();

        // exp + row sum (zero pad cols >= 201)
        {
          int q = tid & 31, kg = tid >> 5;
          float mr = mrow[q];
          float psum = 0.f;
#pragma unroll
          for (int j2=0; j2<7; ++j2){
            int k = kg + 32*j2;
            float pe = 0.f;
            if (k < NTOK) pe = __expf(bf2f(Sb[q*232 + k]) - mr);
            psum += pe;
            Sb[q*232 + k] = f2bf(pe);
          }
          psum += __shfl_xor(psum, 32);
          if (!(tid & 32)) red[wv*33 + q] = psum;
        }
        __syncthreads();
        if (tid < 32){
          float s = red[tid];
#pragma unroll
          for (int w=1; w<16; ++w) s += red[w*33 + tid];
          dsum[tid] = s;
        }
        __syncthreads();

        // PV (waves 0-3)
        if (wv < 4){
          int mf2 = wv & 1, nf = wv >> 1;
          f32x4 oA = (f32x4){0,0,0,0}, oB = (f32x4){0,0,0,0};
#pragma unroll
          for (int kf=0; kf<7; ++kf){
            bfrag pa = *(const bfrag*)(Sb + (mf2*16 + (lane&15))*232 + kf*32 + 8*(lane>>4));
            bfrag vb = *(const bfrag*)(Vt + (nf*16 + (lane&15))*232 + kf*32 + 8*(lane>>4));
            if (kf & 1) oB = __builtin_amdgcn_mfma_f32_16x16x32_bf16(pa, vb, oB, 0,0,0);
            else        oA = __builtin_amdgcn_mfma_f32_16x16x32_bf16(pa, vb, oA, 0,0,0);
          }
          f32x4 o = oA + oB;
          int d = nf*16 + (lane & 15);
#pragma unroll
          for (int reg=0; reg<4; ++reg){
            int q = mf2*16 + 4*(lane>>4) + reg;
            Ob[q*40 + d] = f2bf(o[reg] * (1.0f/dsum[q]));
          }
        }
        __syncthreads();

        // Wo fold into accW[mt] (all 16 waves, 2 mfma)
        {
          bfrag oa = *(const bfrag*)(Ob + (mfw*16 + (lane&15))*40 + 8*(lane>>4));
          accW[mt] = __builtin_amdgcn_mfma_f32_16x16x32_bf16(oa, wobh, accW[mt], 0,0,0);
          accW[mt] = __builtin_amdgcn_mfma_f32_16x16x32_bf16(oa, wobl, accW[mt], 0,0,0);
        }
        __syncthreads();
      } // mt
    } // h

    // ---- apply attention delta + bo ----
    {
      int j = ngw*16 + (lane & 15);
      float boj = bo[j];
#pragma unroll
      for (int mt=0; mt<7; ++mt){
#pragma unroll
        for (int reg=0; reg<4; ++reg){
          int t = mt*32 + mfw*16 + 4*(lane>>4) + reg;
          if (t < NTOK) xs[t*LDX + j] += accW[mt][reg] + boj;
        }
      }
    }
    __syncthreads();

    ln_stats(xs, s_m, s_r, tid);   // ln2
    __syncthreads();

    // ---- gate ----
    if (tid < NTOK){
      const float* row = xs + tid*LDX;
      float m = s_m[tid], r = s_r[tid];
      float gl[NEXP];
#pragma unroll
      for (int x=0;x<NEXP;++x) gl[x] = bg[x];
      for (int e=0;e<EDIM;++e){
        float hv = (row[e]-m)*r*ln2w[e] + ln2b[e];
#pragma unroll
        for (int x=0;x<NEXP;++x) gl[x] += hv*Wg[e*NEXP+x];
      }
      float gm = gl[0];
#pragma unroll
      for (int x=1;x<NEXP;++x) gm = fmaxf(gm, gl[x]);
      float gs = 0.f;
#pragma unroll
      for (int x=0;x<NEXP;++x){ gl[x] = __expf(gl[x]-gm); gs += gl[x]; }
      float gi = 1.0f/gs;
#pragma unroll
      for (int x=0;x<NEXP;++x) gateb[tid*NEXP+x] = gl[x]*gi;
    }
    __syncthreads();

    // ---- MoE: MFMA, 32-token tiles, 16 waves ----
    const int mfg = wv >> 3, nfg = wv & 7;
    for (int t0 = 0; t0 < NTOK; t0 += 32){
      // A-stage (first 512 threads, original packing)
      if (tid < 512){
        int mf = tid >> 8;
        int row = (tid & 15) + 16*mf;
        int kb  = ((tid>>6)&3)*32 + 8*((tid>>4)&3);
        int t = t0 + row;
        union { unsigned short u[8]; bfrag v; } hu, lu;
        if (t < NTOK){
          float m = s_m[t], r = s_r[t];
          const float* xr = &xs[t*LDX + kb];
          float4 a = *(const float4*)xr;
          float4 bq4 = *(const float4*)(xr+4);
          float4 w0 = *(const float4*)(ln2w + kb);
          float4 w1 = *(const float4*)(ln2w + kb + 4);
          float4 bb0 = *(const float4*)(ln2b + kb);
          float4 bb1 = *(const float4*)(ln2b + kb + 4);
          float vv[8] = {(a.x-m)*r*w0.x+bb0.x, (a.y-m)*r*w0.y+bb0.y,
                         (a.z-m)*r*w0.z+bb0.z, (a.w-m)*r*w0.w+bb0.w,
                         (bq4.x-m)*r*w1.x+bb1.x, (bq4.y-m)*r*w1.y+bb1.y,
                         (bq4.z-m)*r*w1.z+bb1.z, (bq4.w-m)*r*w1.w+bb1.w};
#pragma unroll
          for (int j=0;j<8;++j){
            unsigned short hb = f2bf(vv[j]);
            hu.u[j] = hb;
            lu.u[j] = f2bf(vv[j] - bf2f(hb));
          }
        } else {
#pragma unroll
          for (int j=0;j<8;++j){ hu.u[j]=0; lu.u[j]=0; }
        }
        *(bfrag*)(Ahi + tid*8) = hu.v;
        *(bfrag*)(Alo + tid*8) = lu.v;
      }
      __syncthreads();

      f32x4 a2a = (f32x4){0,0,0,0}, a2b = (f32x4){0,0,0,0};

      for (int x = 0; x < NEXP; ++x){
        const unsigned short* W1hx = p.W1h + (size_t)(li*NEXP+x)*FFD*EDIM;
        const unsigned short* W1lx = p.W1l + (size_t)(li*NEXP+x)*FFD*EDIM;
        const unsigned short* W2hx = p.W2h + (size_t)(li*NEXP+x)*EDIM*FFD;
        const unsigned short* W2lx = p.W2l + (size_t)(li*NEXP+x)*EDIM*FFD;

        // GEMM1: wave owns n-frag nf = wv (16 frags over 256 cols)
        f32x4 a1a[2], a1b[2];
#pragma unroll
        for (int i=0;i<2;++i){ a1a[i]=(f32x4){0,0,0,0}; a1b[i]=(f32x4){0,0,0,0}; }
#pragma unroll
        for (int kf=0;kf<4;++kf){
          bfrag ah[2], al[2];
#pragma unroll
          for (int mf=0;mf<2;++mf){
            ah[mf] = *(const bfrag*)(Ahi + ((mf*4+kf)*64 + lane)*8);
            al[mf] = *(const bfrag*)(Alo + ((mf*4+kf)*64 + lane)*8);
          }
          size_t n = (size_t)(wv*16 + (lane&15));
          size_t off = n*128 + kf*32 + 8*(lane>>4);
          bfrag bh = *(const bfrag*)(W1hx + off);
          bfrag bl = *(const bfrag*)(W1lx + off);
#pragma unroll
          for (int mf=0;mf<2;++mf){
            if (kf & 1){
              a1b[mf] = __builtin_amdgcn_mfma_f32_16x16x32_bf16(ah[mf], bh, a1b[mf], 0,0,0);
              a1b[mf] = __builtin_amdgcn_mfma_f32_16x16x32_bf16(ah[mf], bl, a1b[mf], 0,0,0);
              a1b[mf] = __builtin_amdgcn_mfma_f32_16x16x32_bf16(al[mf], bh, a1b[mf], 0,0,0);
            } else {
              a1a[mf] = __builtin_amdgcn_mfma_f32_16x16x32_bf16(ah[mf], bh, a1a[mf], 0,0,0);
              a1a[mf] = __builtin_amdgcn_mfma_f32_16x16x32_bf16(ah[mf], bl, a1a[mf], 0,0,0);
              a1a[mf] = __builtin_amdgcn_mfma_f32_16x16x32_bf16(al[mf], bh, a1a[mf], 0,0,0);
            }
          }
        }
        // epilogue: bias, relu, gate, hi/lo split, scatter to hid frag layout
        {
          int c = lane & 15;
          int n = wv*16 + c;
          float bb = b1g[x*FFD + n];
#pragma unroll
          for (int mf=0;mf<2;++mf){
            f32x4 s = a1a[mf] + a1b[mf];
#pragma unroll
            for (int reg=0;reg<4;++reg){
              int msub = (lane>>4)*4 + reg;
              int t = t0 + mf*16 + msub;
              float g = (t < NTOK) ? gateb[t*NEXP+x] : 0.f;
              float v = fmaxf(s[reg] + bb, 0.f) * g;
              unsigned short hb = f2bf(v);
              unsigned short lb = f2bf(v - bf2f(hb));
              int idx = ((mf*8 + (n>>5))*64 + msub + 16*((n>>3)&3))*8 + (n&7);
              Hh[idx] = hb; Hl[idx] = lb;
            }
          }
        }
        __syncthreads();

        // GEMM2: wave owns (mfg, nfg); acc across experts
#pragma unroll
        for (int kf=0;kf<8;++kf){
          bfrag hh = *(const bfrag*)(Hh + ((mfg*8+kf)*64 + lane)*8);
          bfrag hl = *(const bfrag*)(Hl + ((mfg*8+kf)*64 + lane)*8);
          size_t off = (size_t)(nfg*16 + (lane&15))*256 + kf*32 + 8*(lane>>4);
          bfrag wh = *(const bfrag*)(W2hx + off);
          bfrag wl = *(const bfrag*)(W2lx + off);
          if (kf & 1){
            a2b = __builtin_amdgcn_mfma_f32_16x16x32_bf16(hh, wh, a2b, 0,0,0);
            a2b = __builtin_amdgcn_mfma_f32_16x16x32_bf16(hh, wl, a2b, 0,0,0);
            a2b = __builtin_amdgcn_mfma_f32_16x16x32_bf16(hl, wh, a2b, 0,0,0);
          } else {
            a2a = __builtin_amdgcn_mfma_f32_16x16x32_bf16(hh, wh, a2a, 0,0,0);
            a2a = __builtin_amdgcn_mfma_f32_16x16x32_bf16(hh, wl, a2a, 0,0,0);
            a2a = __builtin_amdgcn_mfma_f32_16x16x32_bf16(hl, wh, a2a, 0,0,0);
          }
        }
        __syncthreads();   // hid free for next expert
      } // x

      // tile epilogue: + sum_x g*b2, RMW xs
      {
        int c = lane & 15;
        int n = nfg*16 + c;
#pragma unroll
        for (int reg=0;reg<4;++reg){
          int t = t0 + mfg*16 + (lane>>4)*4 + reg;
          if (t < NTOK){
            float bs = 0.f;
#pragma unroll
            for (int x=0;x<NEXP;++x) bs += gateb[t*NEXP+x]*b2g[x*EDIM+n];
            xs[t*LDX+n] += a2a[reg] + a2b[reg] + bs;
          }
        }
      }
      __syncthreads();
    } // tiles
  } // layers

  if (tid < EDIM) p.out[b*EDIM + tid] = xs[200*LDX + tid];
}

extern "C" void kernel_launch(void* const* d_in, const int* in_sizes, int n_in,
                              void* d_out, int out_size, void* d_ws, size_t ws_size,
                              hipStream_t stream) {
  (void)in_sizes; (void)n_in; (void)out_size; (void)ws_size;
  char* ws = (char*)d_ws;

  const float* Wqkv = (const float*)d_in[11];
  const float* bqkv = (const float*)d_in[12];
  const float* Wo   = (const float*)d_in[13];
  const float* W1   = (const float*)d_in[19];
  const float* W2   = (const float*)d_in[21];

  hipLaunchKernelGGL(prep_qkv_bf, dim3(6*384), dim3(128), 0, stream,
                     Wqkv, bqkv,
                     (unsigned short*)(ws+OFF_WQH), (unsigned short*)(ws+OFF_WQL),
                     (float*)(ws+OFF_BQ));
  hipLaunchKernelGGL(prep_wo_bf, dim3(384), dim3(256), 0, stream, Wo,
                     (unsigned short*)(ws+OFF_WOH), (unsigned short*)(ws+OFF_WOL));
  hipLaunchKernelGGL(prep_moe, dim3(3840), dim3(256), 0, stream, W1, W2,
                     (unsigned short*)(ws+OFF_W1H), (unsigned short*)(ws+OFF_W1L),
                     (unsigned short*)(ws+OFF_W2H), (unsigned short*)(ws+OFF_W2L));

  Params p;
  p.x_cat        = (const int*)  d_in[0];
  p.x_num        = (const float*)d_in[1];
  p.x_eng        = (const float*)d_in[2];
  p.emb          = (const float*)d_in[3];
  p.emb_bias     = (const float*)d_in[4];
  p.emb_eng      = (const float*)d_in[5];
  p.emb_bias_eng = (const float*)d_in[6];
  p.ln0w = (const float*)d_in[7];  p.ln0b = (const float*)d_in[8];
  p.ln1w = (const float*)d_in[9];  p.ln1b = (const float*)d_in[10];
  p.ln2w = (const float*)d_in[15]; p.ln2b = (const float*)d_in[16];
  p.bo   = (const float*)d_in[14];
  p.Wg   = (const float*)d_in[17]; p.bg = (const float*)d_in[18];
  p.b1   = (const float*)d_in[20]; p.b2 = (const float*)d_in[22];
  p.Wqh = (const unsigned short*)(ws+OFF_WQH);
  p.Wql = (const unsigned short*)(ws+OFF_WQL);
  p.bq  = (const float*)(ws+OFF_BQ);
  p.Woh = (const unsigned short*)(ws+OFF_WOH);
  p.Wol = (const unsigned short*)(ws+OFF_WOL);
  p.W1h = (const unsigned short*)(ws+OFF_W1H);
  p.W1l = (const unsigned short*)(ws+OFF_W1L);
  p.W2h = (const unsigned short*)(ws+OFF_W2H);
  p.W2l = (const unsigned short*)(ws+OFF_W2L);
  p.out = (float*)d_out;

  hipLaunchKernelGGL(fam_fwd, dim3(NB), dim3(1024), 0, stream, p);
}

// Round 8
// 8069.749 us; speedup vs baseline: 1.0029x; 1.0029x over previous
//
#include <hip/hip_runtime.h>
#include <math.h>

#define NTOK 201
#define EDIM 128
#define LDX  132
#define NHEAD 4
#define HD   32
#define NLAY 6
#define NEXP 5
#define FFD  256
#define NCAT 53
#define NNUM 47
#define NENG 100
#define NEMB 1352
#define SEQL 51
#define NB   512
#define LN_EPS 1e-5f
#define SCALE 0.17677669529663687f

typedef __attribute__((ext_vector_type(8))) short bfrag;           // 8 bf16
typedef __attribute__((ext_vector_type(4))) float f32x4;           // mfma acc
typedef __attribute__((ext_vector_type(8))) unsigned short u16x8;
typedef __attribute__((ext_vector_type(4))) unsigned short u16x4;

__device__ __forceinline__ float bf2f(unsigned short u){ return __uint_as_float(((unsigned)u)<<16); }
__device__ __forceinline__ unsigned short f2bf(float f){
  unsigned u = __float_as_uint(f);
  return (unsigned short)((u + 0x7FFFu + ((u>>16)&1u)) >> 16);
}

// ---------------- workspace layout (bytes) ----------------
#define OFF_WQH  0u            // Wqkv hi  [6][384][128] bf16 (Q rows pre-scaled)
#define OFF_WQL  589824u       // Wqkv lo
#define OFF_BQ   1179648u      // bqkv f32 [6][384]
#define OFF_WOH  1188864u      // Wo hi [6][128][128] bf16 ([j][d])
#define OFF_WOL  1385472u
#define OFF_W1H  1582080u      // W1T hi [6][5][256][128] bf16
#define OFF_W1L  3548160u
#define OFF_W2H  5514240u      // W2T hi [6][5][128][256] bf16
#define OFF_W2L  7480320u

// ---------------- prep kernels ----------------
__global__ void prep_qkv_bf(const float* __restrict__ Wqkv, const float* __restrict__ bqkv,
                            unsigned short* __restrict__ Wqh, unsigned short* __restrict__ Wql,
                            float* __restrict__ bq){
  int bid = blockIdx.x; int n = bid % 384; int e = threadIdx.x;
  float sc = (n < 128) ? SCALE : 1.0f;
  float w = Wqkv[(size_t)bid*128 + e] * sc;
  unsigned short h = f2bf(w), l = f2bf(w - bf2f(h));
  Wqh[(size_t)bid*128 + e] = h; Wql[(size_t)bid*128 + e] = l;
  if (e == 0) bq[bid] = bqkv[bid] * sc;
}

__global__ void prep_wo_bf(const float* __restrict__ Wo,
                           unsigned short* __restrict__ Woh, unsigned short* __restrict__ Wol){
  int idx = blockIdx.x*blockDim.x + threadIdx.x;
  if (idx >= 6*128*128) return;
  float w = Wo[idx];
  unsigned short h = f2bf(w), l = f2bf(w - bf2f(h));
  Woh[idx] = h; Wol[idx] = l;
}

__global__ void prep_moe(const float* __restrict__ W1, const float* __restrict__ W2,
                         unsigned short* __restrict__ W1h, unsigned short* __restrict__ W1l,
                         unsigned short* __restrict__ W2h, unsigned short* __restrict__ W2l){
  const int Ntot = 6*5*128*256;
  for (int idx = blockIdx.x*blockDim.x + threadIdx.x; idx < Ntot; idx += gridDim.x*blockDim.x){
    int lx = idx / 32768; int rem = idx & 32767; int e = rem >> 8; int f = rem & 255;
    float w = W1[idx];
    unsigned short h = f2bf(w); unsigned short l = f2bf(w - bf2f(h));
    size_t o1 = (size_t)(lx*256+f)*128 + e;
    W1h[o1] = h; W1l[o1] = l;
    int f2 = (idx >> 7) & 255; int e2 = idx & 127;
    float w2 = W2[idx];
    unsigned short h2 = f2bf(w2); unsigned short l2 = f2bf(w2 - bf2f(h2));
    size_t o2 = (size_t)(lx*128+e2)*256 + f2;
    W2h[o2] = h2; W2l[o2] = l2;
  }
}

// ---------------- main kernel ----------------
struct Params {
  const int*   x_cat;
  const float* x_num;
  const float* x_eng;
  const float* emb;
  const float* emb_bias;
  const float* emb_eng;
  const float* emb_bias_eng;
  const float* ln0w; const float* ln0b;
  const float* ln1w; const float* ln1b;
  const float* ln2w; const float* ln2b;
  const float* bo;
  const float* Wg;   const float* bg;
  const float* b1;   const float* b2;
  const unsigned short* Wqh; const unsigned short* Wql; const float* bq;
  const unsigned short* Woh; const unsigned short* Wol;
  const unsigned short* W1h; const unsigned short* W1l;
  const unsigned short* W2h; const unsigned short* W2l;
  float* out;
};

__device__ __forceinline__ void ln_stats(const float* xs, float* s_m, float* s_r, int tid){
  if (tid < NTOK){
    const float* row = xs + tid*LDX;
    float s0=0,s1=0,s2=0,s3=0;
    for (int e=0;e<EDIM;e+=4){ s0+=row[e]; s1+=row[e+1]; s2+=row[e+2]; s3+=row[e+3]; }
    float m = (s0+s1+s2+s3)*(1.0f/EDIM);
    float v0=0,v1=0,v2=0,v3=0;
    for (int e=0;e<EDIM;e+=4){
      float d0=row[e]-m,d1=row[e+1]-m,d2=row[e+2]-m,d3=row[e+3]-m;
      v0+=d0*d0; v1+=d1*d1; v2+=d2*d2; v3+=d3*d3;
    }
    s_m[tid]=m; s_r[tid]=1.0f/sqrtf((v0+v1+v2+v3)*(1.0f/EDIM)+LN_EPS);
  }
}

// 1024-thread staging of a 32-row LN'd tile, hi/lo bf16, 4 elems/thread
__device__ __forceinline__ void stage_ht(const float* xs, const float* s_m, const float* s_r,
                                         unsigned short* HTh, unsigned short* HTl,
                                         const float* lw, const float* lb, int t0, int tid){
  int row = tid >> 5;            // 0..31
  int c4  = (tid & 31) << 2;     // 0..124
  int t = t0 + row;
  u16x4 hu = (u16x4){0,0,0,0}, lu = (u16x4){0,0,0,0};
  if (t < NTOK){
    float m = s_m[t], r = s_r[t];
    float4 a  = *(const float4*)(&xs[t*LDX + c4]);
    float4 w  = *(const float4*)(lw + c4);
    float4 bb = *(const float4*)(lb + c4);
    float v0 = (a.x-m)*r*w.x + bb.x;
    float v1 = (a.y-m)*r*w.y + bb.y;
    float v2 = (a.z-m)*r*w.z + bb.z;
    float v3 = (a.w-m)*r*w.w + bb.w;
    unsigned short h0=f2bf(v0), h1=f2bf(v1), h2=f2bf(v2), h3=f2bf(v3);
    hu = (u16x4){h0,h1,h2,h3};
    lu = (u16x4){f2bf(v0-bf2f(h0)), f2bf(v1-bf2f(h1)), f2bf(v2-bf2f(h2)), f2bf(v3-bf2f(h3))};
  }
  *(u16x4*)(HTh + row*136 + c4) = hu;
  *(u16x4*)(HTl + row*136 + c4) = lu;
}

__global__ __launch_bounds__(1024) __attribute__((amdgpu_waves_per_eu(4,4)))
void fam_fwd(Params p){
  __shared__ float xs[NTOK*LDX];          // 106,128 B
  __shared__ float s_m[NTOK], s_r[NTOK];  // 1,608 B
  __shared__ __align__(16) char scb[55296];

  const int b = blockIdx.x, tid = threadIdx.x;
  const int lane = tid & 63, wv = tid >> 6;   // wv 0..15

  // ---- Phase 0: embeddings ----
  {
    const int e = tid & 127, tl = tid >> 7;   // 8 rows per pass
    for (int t = tl; t < NTOK; t += 8){
      float v;
      if (t < NCAT){
        int idx = p.x_cat[b*(SEQL*NCAT) + (SEQL-1)*NCAT + t];
        v = p.emb[idx*EDIM+e] + p.emb_bias[t*EDIM+e];
      } else if (t < NCAT+NNUM){
        int j = t - NCAT;
        float nv = p.x_num[b*(SEQL*NNUM)+(SEQL-1)*NNUM+j];
        v = p.emb[(NEMB-NNUM+1+j)*EDIM+e]*nv + p.emb_bias[(NCAT+j)*EDIM+e];
      } else if (t < NCAT+NNUM+NENG){
        int j = t - (NCAT+NNUM);
        float ev = p.x_eng[b*NENG+j];
        v = p.emb_eng[j*EDIM+e]*ev + p.emb_bias_eng[j*EDIM+e];
      } else v = 0.f;
      xs[t*LDX+e] = v;
    }
  }
  __syncthreads();
  ln_stats(xs, s_m, s_r, tid);
  __syncthreads();
  {
    const int e = tid & 127, tl = tid >> 7;
    for (int t = tl; t < NTOK; t += 8){
      float m = s_m[t], r = s_r[t];
      xs[t*LDX+e] = (xs[t*LDX+e]-m)*r*p.ln0w[e] + p.ln0b[e];
    }
  }
  __syncthreads();

  // ---- attn LDS pointers ----
  unsigned short* Kh  = (unsigned short*)scb;                    // [224][40]
  unsigned short* Vt  = (unsigned short*)(scb + 17920);          // [32][232]
  unsigned short* HTh = (unsigned short*)(scb + 32768);          // [32][136]
  unsigned short* HTl = (unsigned short*)(scb + 32768 + 8704);   // [32][136]
  unsigned short* Sb  = (unsigned short*)(scb + 32768);          // [32][232] (aliases HT)
  unsigned short* Ob  = (unsigned short*)(scb + 32768 + 14848);  // [32][40]
  unsigned short* Qmh = (unsigned short*)(scb + 50176);          // [32][40]
  unsigned short* Qml = (unsigned short*)(scb + 52736);          // [32][40]
  float* red  = (float*)(scb + 52736);                           // [16][33] (aliases Qml)
  float* mrow = (float*)(scb + 52736 + 2112);                    // [32]
  float* dsum = (float*)(scb + 52736 + 2240);                    // [32]
  // ---- moe LDS pointers ----
  unsigned short* Ahi = (unsigned short*)scb;
  unsigned short* Alo = (unsigned short*)(scb + 8192);
  unsigned short* Hh  = (unsigned short*)(scb + 16384);
  unsigned short* Hl  = (unsigned short*)(scb + 32768);
  float*          gateb = (float*)(scb + 49152);

  for (int li = 0; li < NLAY; ++li){
    const float* ln1w = p.ln1w + li*EDIM;
    const float* ln1b = p.ln1b + li*EDIM;
    const float* ln2w = p.ln2w + li*EDIM;
    const float* ln2b = p.ln2b + li*EDIM;
    const float* bo   = p.bo + li*EDIM;
    const float* Wg   = p.Wg + li*EDIM*NEXP;
    const float* bg   = p.bg + li*NEXP;
    const float* b1g  = p.b1 + li*NEXP*FFD;
    const float* b2g  = p.b2 + li*NEXP*EDIM;

    ln_stats(xs, s_m, s_r, tid);   // ln1
    __syncthreads();

    f32x4 accW[7];                 // Wo-folded attention delta: wave owns (mfw, jfrag=ngw)
#pragma unroll
    for (int mt=0; mt<7; ++mt) accW[mt]=(f32x4){0,0,0,0};

    const int mfw = wv & 1;
    const int ngw = wv >> 1;       // 0..7

    for (int h = 0; h < NHEAD; ++h){
      // ======== pass 1: K and V (waves 0-7 compute; all stage) ========
      bfrag wbh[4], wbl[4]; float bias1 = 0.f;
      if (wv < 8){
        int sel = wv >> 1;
        int nrow = ((sel < 2) ? (128 + h*HD + sel*16) : (256 + h*HD + (sel-2)*16)) + (lane & 15);
        const unsigned short* Bh = p.Wqh + ((size_t)li*384 + nrow)*128 + 8*(lane>>4);
        const unsigned short* Bl = p.Wql + ((size_t)li*384 + nrow)*128 + 8*(lane>>4);
#pragma unroll
        for (int kf=0; kf<4; ++kf){ wbh[kf] = *(const bfrag*)(Bh + kf*32); wbl[kf] = *(const bfrag*)(Bl + kf*32); }
        bias1 = p.bq[li*384 + nrow];
      }

      for (int mt=0; mt<7; ++mt){
        stage_ht(xs, s_m, s_r, HTh, HTl, ln1w, ln1b, mt*32, tid);
        __syncthreads();
        if (wv < 8){
          int sel = wv >> 1, mf1 = wv & 1;
          f32x4 aA = (f32x4){0,0,0,0}, aB = (f32x4){0,0,0,0};
#pragma unroll
          for (int kf=0; kf<4; ++kf){
            bfrag ah = *(const bfrag*)(HTh + (mf1*16 + (lane&15))*136 + kf*32 + 8*(lane>>4));
            bfrag av = *(const bfrag*)(HTl + (mf1*16 + (lane&15))*136 + kf*32 + 8*(lane>>4));
            if (kf & 1){
              aB = __builtin_amdgcn_mfma_f32_16x16x32_bf16(ah, wbh[kf], aB, 0,0,0);
              aB = __builtin_amdgcn_mfma_f32_16x16x32_bf16(ah, wbl[kf], aB, 0,0,0);
              aB = __builtin_amdgcn_mfma_f32_16x16x32_bf16(av, wbh[kf], aB, 0,0,0);
            } else {
              aA = __builtin_amdgcn_mfma_f32_16x16x32_bf16(ah, wbh[kf], aA, 0,0,0);
              aA = __builtin_amdgcn_mfma_f32_16x16x32_bf16(ah, wbl[kf], aA, 0,0,0);
              aA = __builtin_amdgcn_mfma_f32_16x16x32_bf16(av, wbh[kf], aA, 0,0,0);
            }
          }
          f32x4 acc = aA + aB;
          int col = lane & 15;
          if (sel < 2){
            int d = sel*16 + col;
#pragma unroll
            for (int reg=0; reg<4; ++reg){
              int tok = mt*32 + mf1*16 + 4*(lane>>4) + reg;
              Kh[tok*40 + d] = f2bf(acc[reg] + bias1);
            }
          } else {
            int d = (sel-2)*16 + col;
            int tokb = mt*32 + mf1*16 + 4*(lane>>4);
            u16x4 pk;
#pragma unroll
            for (int reg=0; reg<4; ++reg) pk[reg] = f2bf(acc[reg] + bias1);
            *(u16x4*)(Vt + d*232 + tokb) = pk;
          }
        }
        __syncthreads();
      }

      // ======== pass 2 ========
      // Wo B-frag: wave owns j-frag ngw
      bfrag wobh, wobl;
      {
        int j = ngw*16 + (lane&15);
        const unsigned short* wb = p.Woh + ((size_t)li*128 + j)*128 + h*HD + 8*(lane>>4);
        const unsigned short* wl = p.Wol + ((size_t)li*128 + j)*128 + h*HD + 8*(lane>>4);
        wobh = *(const bfrag*)wb; wobl = *(const bfrag*)wl;
      }

#pragma unroll
      for (int mt=0; mt<7; ++mt){
        stage_ht(xs, s_m, s_r, HTh, HTl, ln1w, ln1b, mt*32, tid);
        __syncthreads();

        // Q-GEMM (waves 0-3)
        if (wv < 4){
          int mf2 = wv & 1, nf = wv >> 1;
          int nrow = h*HD + nf*16 + (lane & 15);
          const unsigned short* Bh = p.Wqh + ((size_t)li*384 + nrow)*128 + 8*(lane>>4);
          const unsigned short* Bl = p.Wql + ((size_t)li*384 + nrow)*128 + 8*(lane>>4);
          f32x4 aA = (f32x4){0,0,0,0}, aB = (f32x4){0,0,0,0};
#pragma unroll
          for (int kf=0; kf<4; ++kf){
            bfrag ah = *(const bfrag*)(HTh + (mf2*16 + (lane&15))*136 + kf*32 + 8*(lane>>4));
            bfrag av = *(const bfrag*)(HTl + (mf2*16 + (lane&15))*136 + kf*32 + 8*(lane>>4));
            bfrag bh = *(const bfrag*)(Bh + kf*32);
            bfrag bl = *(const bfrag*)(Bl + kf*32);
            if (kf & 1){
              aB = __builtin_amdgcn_mfma_f32_16x16x32_bf16(ah, bh, aB, 0,0,0);
              aB = __builtin_amdgcn_mfma_f32_16x16x32_bf16(ah, bl, aB, 0,0,0);
              aB = __builtin_amdgcn_mfma_f32_16x16x32_bf16(av, bh, aB, 0,0,0);
            } else {
              aA = __builtin_amdgcn_mfma_f32_16x16x32_bf16(ah, bh, aA, 0,0,0);
              aA = __builtin_amdgcn_mfma_f32_16x16x32_bf16(ah, bl, aA, 0,0,0);
              aA = __builtin_amdgcn_mfma_f32_16x16x32_bf16(av, bh, aA, 0,0,0);
            }
          }
          f32x4 acc = aA + aB;
          float bias = p.bq[li*384 + h*HD + nf*16 + (lane&15)];
          int d = nf*16 + (lane & 15);
#pragma unroll
          for (int reg=0; reg<4; ++reg){
            float v = acc[reg] + bias;
            unsigned short hb = f2bf(v);
            int qrow = mf2*16 + 4*(lane>>4) + reg;
            Qmh[qrow*40 + d] = hb;
            Qml[qrow*40 + d] = f2bf(v - bf2f(hb));
          }
        }
        __syncthreads();

        // scores: all 16 waves; wave covers nf in {ngw, ngw+8}
        {
          bfrag qh = *(const bfrag*)(Qmh + (mfw*16 + (lane&15))*40 + 8*(lane>>4));
          bfrag ql = *(const bfrag*)(Qml + (mfw*16 + (lane&15))*40 + 8*(lane>>4));
#pragma unroll
          for (int rep=0; rep<2; ++rep){
            int nf = ngw + 8*rep;
            if (nf < 14){
              bfrag kb = *(const bfrag*)(Kh + (nf*16 + (lane&15))*40 + 8*(lane>>4));
              f32x4 s = (f32x4){0,0,0,0};
              s = __builtin_amdgcn_mfma_f32_16x16x32_bf16(qh, kb, s, 0,0,0);
              s = __builtin_amdgcn_mfma_f32_16x16x32_bf16(ql, kb, s, 0,0,0);
              int tok = nf*16 + (lane & 15);
#pragma unroll
              for (int reg=0; reg<4; ++reg){
                int q = mfw*16 + 4*(lane>>4) + reg;
                Sb[q*232 + tok] = f2bf(s[reg]);
              }
            }
          }
        }
        __syncthreads();

        // row max
        {
          int q = tid & 31, kg = tid >> 5;
          float pmax = -INFINITY;
#pragma unroll
          for (int j2=0; j2<7; ++j2){
            int k = kg + 32*j2;
            if (k < NTOK) pmax = fmaxf(pmax, bf2f(Sb[q*232 + k]));
          }
          pmax = fmaxf(pmax, __shfl_xor(pmax, 32));
          if (!(tid & 32)) red[wv*33 + q] = pmax;
        }
        __syncthreads();
        if (tid < 32){
          float m = red[tid];
#pragma unroll
          for (int w=1; w<16; ++w) m = fmaxf(m, red[w*33 + tid]);
          mrow[tid] = m;
        }
        __syncthreads();

        // exp + row sum (zero pad cols >= 201)
        {
          int q = tid & 31, kg = tid >> 5;
          float mr = mrow[q];
          float psum = 0.f;
#pragma unroll
          for (int j2=0; j2<7; ++j2){
            int k = kg + 32*j2;
            float pe = 0.f;
            if (k < NTOK) pe = __expf(bf2f(Sb[q*232 + k]) - mr);
            psum += pe;
            Sb[q*232 + k] = f2bf(pe);
          }
          psum += __shfl_xor(psum, 32);
          if (!(tid & 32)) red[wv*33 + q] = psum;
        }
        __syncthreads();
        if (tid < 32){
          float s = red[tid];
#pragma unroll
          for (int w=1; w<16; ++w) s += red[w*33 + tid];
          dsum[tid] = s;
        }
        __syncthreads();

        // PV (waves 0-3)
        if (wv < 4){
          int mf2 = wv & 1, nf = wv >> 1;
          f32x4 oA = (f32x4){0,0,0,0}, oB = (f32x4){0,0,0,0};
#pragma unroll
          for (int kf=0; kf<7; ++kf){
            bfrag pa = *(const bfrag*)(Sb + (mf2*16 + (lane&15))*232 + kf*32 + 8*(lane>>4));
            bfrag vb = *(const bfrag*)(Vt + (nf*16 + (lane&15))*232 + kf*32 + 8*(lane>>4));
            if (kf & 1) oB = __builtin_amdgcn_mfma_f32_16x16x32_bf16(pa, vb, oB, 0,0,0);
            else        oA = __builtin_amdgcn_mfma_f32_16x16x32_bf16(pa, vb, oA, 0,0,0);
          }
          f32x4 o = oA + oB;
          int d = nf*16 + (lane & 15);
#pragma unroll
          for (int reg=0; reg<4; ++reg){
            int q = mf2*16 + 4*(lane>>4) + reg;
            Ob[q*40 + d] = f2bf(o[reg] * (1.0f/dsum[q]));
          }
        }
        __syncthreads();

        // Wo fold into accW[mt] (all 16 waves, 2 mfma)
        {
          bfrag oa = *(const bfrag*)(Ob + (mfw*16 + (lane&15))*40 + 8*(lane>>4));
          accW[mt] = __builtin_amdgcn_mfma_f32_16x16x32_bf16(oa, wobh, accW[mt], 0,0,0);
          accW[mt] = __builtin_amdgcn_mfma_f32_16x16x32_bf16(oa, wobl, accW[mt], 0,0,0);
        }
        __syncthreads();
      } // mt
    } // h

    // ---- apply attention delta + bo ----
    {
      int j = ngw*16 + (lane & 15);
      float boj = bo[j];
#pragma unroll
      for (int mt=0; mt<7; ++mt){
#pragma unroll
        for (int reg=0; reg<4; ++reg){
          int t = mt*32 + mfw*16 + 4*(lane>>4) + reg;
          if (t < NTOK) xs[t*LDX + j] += accW[mt][reg] + boj;
        }
      }
    }
    __syncthreads();

    ln_stats(xs, s_m, s_r, tid);   // ln2
    __syncthreads();

    // ---- gate ----
    if (tid < NTOK){
      const float* row = xs + tid*LDX;
      float m = s_m[tid], r = s_r[tid];
      float gl[NEXP];
#pragma unroll
      for (int x=0;x<NEXP;++x) gl[x] = bg[x];
      for (int e=0;e<EDIM;++e){
        float hv = (row[e]-m)*r*ln2w[e] + ln2b[e];
#pragma unroll
        for (int x=0;x<NEXP;++x) gl[x] += hv*Wg[e*NEXP+x];
      }
      float gm = gl[0];
#pragma unroll
      for (int x=1;x<NEXP;++x) gm = fmaxf(gm, gl[x]);
      float gs = 0.f;
#pragma unroll
      for (int x=0;x<NEXP;++x){ gl[x] = __expf(gl[x]-gm); gs += gl[x]; }
      float gi = 1.0f/gs;
#pragma unroll
      for (int x=0;x<NEXP;++x) gateb[tid*NEXP+x] = gl[x]*gi;
    }
    __syncthreads();

    // ---- MoE: MFMA, 32-token tiles, 16 waves ----
    const int mfg = wv >> 3, nfg = wv & 7;
    for (int t0 = 0; t0 < NTOK; t0 += 32){
      // A-stage (first 512 threads, original packing)
      if (tid < 512){
        int mf = tid >> 8;
        int row = (tid & 15) + 16*mf;
        int kb  = ((tid>>6)&3)*32 + 8*((tid>>4)&3);
        int t = t0 + row;
        union { unsigned short u[8]; bfrag v; } hu, lu;
        if (t < NTOK){
          float m = s_m[t], r = s_r[t];
          const float* xr = &xs[t*LDX + kb];
          float4 a = *(const float4*)xr;
          float4 bq4 = *(const float4*)(xr+4);
          float4 w0 = *(const float4*)(ln2w + kb);
          float4 w1 = *(const float4*)(ln2w + kb + 4);
          float4 bb0 = *(const float4*)(ln2b + kb);
          float4 bb1 = *(const float4*)(ln2b + kb + 4);
          float vv[8] = {(a.x-m)*r*w0.x+bb0.x, (a.y-m)*r*w0.y+bb0.y,
                         (a.z-m)*r*w0.z+bb0.z, (a.w-m)*r*w0.w+bb0.w,
                         (bq4.x-m)*r*w1.x+bb1.x, (bq4.y-m)*r*w1.y+bb1.y,
                         (bq4.z-m)*r*w1.z+bb1.z, (bq4.w-m)*r*w1.w+bb1.w};
#pragma unroll
          for (int j=0;j<8;++j){
            unsigned short hb = f2bf(vv[j]);
            hu.u[j] = hb;
            lu.u[j] = f2bf(vv[j] - bf2f(hb));
          }
        } else {
#pragma unroll
          for (int j=0;j<8;++j){ hu.u[j]=0; lu.u[j]=0; }
        }
        *(bfrag*)(Ahi + tid*8) = hu.v;
        *(bfrag*)(Alo + tid*8) = lu.v;
      }
      __syncthreads();

      f32x4 a2a = (f32x4){0,0,0,0}, a2b = (f32x4){0,0,0,0};

      for (int x = 0; x < NEXP; ++x){
        const unsigned short* W1hx = p.W1h + (size_t)(li*NEXP+x)*FFD*EDIM;
        const unsigned short* W1lx = p.W1l + (size_t)(li*NEXP+x)*FFD*EDIM;
        const unsigned short* W2hx = p.W2h + (size_t)(li*NEXP+x)*EDIM*FFD;
        const unsigned short* W2lx = p.W2l + (size_t)(li*NEXP+x)*EDIM*FFD;

        // GEMM1: wave owns n-frag nf = wv (16 frags over 256 cols)
        f32x4 a1a[2], a1b[2];
#pragma unroll
        for (int i=0;i<2;++i){ a1a[i]=(f32x4){0,0,0,0}; a1b[i]=(f32x4){0,0,0,0}; }
#pragma unroll
        for (int kf=0;kf<4;++kf){
          bfrag ah[2], al[2];
#pragma unroll
          for (int mf=0;mf<2;++mf){
            ah[mf] = *(const bfrag*)(Ahi + ((mf*4+kf)*64 + lane)*8);
            al[mf] = *(const bfrag*)(Alo + ((mf*4+kf)*64 + lane)*8);
          }
          size_t n = (size_t)(wv*16 + (lane&15));
          size_t off = n*128 + kf*32 + 8*(lane>>4);
          bfrag bh = *(const bfrag*)(W1hx + off);
          bfrag bl = *(const bfrag*)(W1lx + off);
#pragma unroll
          for (int mf=0;mf<2;++mf){
            if (kf & 1){
              a1b[mf] = __builtin_amdgcn_mfma_f32_16x16x32_bf16(ah[mf], bh, a1b[mf], 0,0,0);
              a1b[mf] = __builtin_amdgcn_mfma_f32_16x16x32_bf16(ah[mf], bl, a1b[mf], 0,0,0);
              a1b[mf] = __builtin_amdgcn_mfma_f32_16x16x32_bf16(al[mf], bh, a1b[mf], 0,0,0);
            } else {
              a1a[mf] = __builtin_amdgcn_mfma_f32_16x16x32_bf16(ah[mf], bh, a1a[mf], 0,0,0);
              a1a[mf] = __builtin_amdgcn_mfma_f32_16x16x32_bf16(ah[mf], bl, a1a[mf], 0,0,0);
              a1a[mf] = __builtin_amdgcn_mfma_f32_16x16x32_bf16(al[mf], bh, a1a[mf], 0,0,0);
            }
          }
        }
        // epilogue: bias, relu, gate, hi/lo split, scatter to hid frag layout
        {
          int c = lane & 15;
          int n = wv*16 + c;
          float bb = b1g[x*FFD + n];
#pragma unroll
          for (int mf=0;mf<2;++mf){
            f32x4 s = a1a[mf] + a1b[mf];
#pragma unroll
            for (int reg=0;reg<4;++reg){
              int msub = (lane>>4)*4 + reg;
              int t = t0 + mf*16 + msub;
              float g = (t < NTOK) ? gateb[t*NEXP+x] : 0.f;
              float v = fmaxf(s[reg] + bb, 0.f) * g;
              unsigned short hb = f2bf(v);
              unsigned short lb = f2bf(v - bf2f(hb));
              int idx = ((mf*8 + (n>>5))*64 + msub + 16*((n>>3)&3))*8 + (n&7);
              Hh[idx] = hb; Hl[idx] = lb;
            }
          }
        }
        __syncthreads();

        // GEMM2: wave owns (mfg, nfg); acc across experts
#pragma unroll
        for (int kf=0;kf<8;++kf){
          bfrag hh = *(const bfrag*)(Hh + ((mfg*8+kf)*64 + lane)*8);
          bfrag hl = *(const bfrag*)(Hl + ((mfg*8+kf)*64 + lane)*8);
          size_t off = (size_t)(nfg*16 + (lane&15))*256 + kf*32 + 8*(lane>>4);
          bfrag wh = *(const bfrag*)(W2hx + off);
          bfrag wl = *(const bfrag*)(W2lx + off);
          if (kf & 1){
            a2b = __builtin_amdgcn_mfma_f32_16x16x32_bf16(hh, wh, a2b, 0,0,0);
            a2b = __builtin_amdgcn_mfma_f32_16x16x32_bf16(hh, wl, a2b, 0,0,0);
            a2b = __builtin_amdgcn_mfma_f32_16x16x32_bf16(hl, wh, a2b, 0,0,0);
          } else {
            a2a = __builtin_amdgcn_mfma_f32_16x16x32_bf16(hh, wh, a2a, 0,0,0);
            a2a = __builtin_amdgcn_mfma_f32_16x16x32_bf16(hh, wl, a2a, 0,0,0);
            a2a = __builtin_amdgcn_mfma_f32_16x16x32_bf16(hl, wh, a2a, 0,0,0);
          }
        }
        __syncthreads();   // hid free for next expert
      } // x

      // tile epilogue: + sum_x g*b2, RMW xs
      {
        int c = lane & 15;
        int n = nfg*16 + c;
#pragma unroll
        for (int reg=0;reg<4;++reg){
          int t = t0 + mfg*16 + (lane>>4)*4 + reg;
          if (t < NTOK){
            float bs = 0.f;
#pragma unroll
            for (int x=0;x<NEXP;++x) bs += gateb[t*NEXP+x]*b2g[x*EDIM+n];
            xs[t*LDX+n] += a2a[reg] + a2b[reg] + bs;
          }
        }
      }
      __syncthreads();
    } // tiles
  } // layers

  if (tid < EDIM) p.out[b*EDIM + tid] = xs[200*LDX + tid];
}

extern "C" void kernel_launch(void* const* d_in, const int* in_sizes, int n_in,
                              void* d_out, int out_size, void* d_ws, size_t ws_size,
                              hipStream_t stream) {
  (void)in_sizes; (void)n_in; (void)out_size; (void)ws_size;
  char* ws = (char*)d_ws;

  const float* Wqkv = (const float*)d_in[11];
  const float* bqkv = (const float*)d_in[12];
  const float* Wo   = (const float*)d_in[13];
  const float* W1   = (const float*)d_in[19];
  const float* W2   = (const float*)d_in[21];

  hipLaunchKernelGGL(prep_qkv_bf, dim3(6*384), dim3(128), 0, stream,
                     Wqkv, bqkv,
                     (unsigned short*)(ws+OFF_WQH), (unsigned short*)(ws+OFF_WQL),
                     (float*)(ws+OFF_BQ));
  hipLaunchKernelGGL(prep_wo_bf, dim3(384), dim3(256), 0, stream, Wo,
                     (unsigned short*)(ws+OFF_WOH), (unsigned short*)(ws+OFF_WOL));
  hipLaunchKernelGGL(prep_moe, dim3(3840), dim3(256), 0, stream, W1, W2,
                     (unsigned short*)(ws+OFF_W1H), (unsigned short*)(ws+OFF_W1L),
                     (unsigned short*)(ws+OFF_W2H), (unsigned short*)(ws+OFF_W2L));

  Params p;
  p.x_cat        = (const int*)  d_in[0];
  p.x_num        = (const float*)d_in[1];
  p.x_eng        = (const float*)d_in[2];
  p.emb          = (const float*)d_in[3];
  p.emb_bias     = (const float*)d_in[4];
  p.emb_eng      = (const float*)d_in[5];
  p.emb_bias_eng = (const float*)d_in[6];
  p.ln0w = (const float*)d_in[7];  p.ln0b = (const float*)d_in[8];
  p.ln1w = (const float*)d_in[9];  p.ln1b = (const float*)d_in[10];
  p.ln2w = (const float*)d_in[15]; p.ln2b = (const float*)d_in[16];
  p.bo   = (const float*)d_in[14];
  p.Wg   = (const float*)d_in[17]; p.bg = (const float*)d_in[18];
  p.b1   = (const float*)d_in[20]; p.b2 = (const float*)d_in[22];
  p.Wqh = (const unsigned short*)(ws+OFF_WQH);
  p.Wql = (const unsigned short*)(ws+OFF_WQL);
  p.bq  = (const float*)(ws+OFF_BQ);
  p.Woh = (const unsigned short*)(ws+OFF_WOH);
  p.Wol = (const unsigned short*)(ws+OFF_WOL);
  p.W1h = (const unsigned short*)(ws+OFF_W1H);
  p.W1l = (const unsigned short*)(ws+OFF_W1L);
  p.W2h = (const unsigned short*)(ws+OFF_W2H);
  p.W2l = (const unsigned short*)(ws+OFF_W2L);
  p.out = (float*)d_out;

  hipLaunchKernelGGL(fam_fwd, dim3(NB), dim3(1024), 0, stream, p);
}

// Round 9
// 5448.082 us; speedup vs baseline: 1.4856x; 1.4812x over previous
//
#include <hip/hip_runtime.h>
#include <math.h>

#define NTOK 201
#define EDIM 128
#define LDX  132
#define NHEAD 4
#define HD   32
#define NLAY 6
#define NEXP 5
#define FFD  256
#define NCAT 53
#define NNUM 47
#define NENG 100
#define NEMB 1352
#define SEQL 51
#define NB   512
#define LN_EPS 1e-5f
#define SCALE 0.17677669529663687f

typedef __attribute__((ext_vector_type(8))) short bfrag;           // 8 bf16
typedef __attribute__((ext_vector_type(4))) float f32x4;           // mfma acc
typedef __attribute__((ext_vector_type(8))) unsigned short u16x8;
typedef __attribute__((ext_vector_type(4))) unsigned short u16x4;

__device__ __forceinline__ float bf2f(unsigned short u){ return __uint_as_float(((unsigned)u)<<16); }
__device__ __forceinline__ unsigned short f2bf(float f){
  unsigned u = __float_as_uint(f);
  return (unsigned short)((u + 0x7FFFu + ((u>>16)&1u)) >> 16);
}

// ---------------- workspace layout (bytes) ----------------
#define OFF_WQH  0u            // Wqkv hi  [6][384][128] bf16 (Q rows pre-scaled)
#define OFF_WQL  589824u       // Wqkv lo
#define OFF_BQ   1179648u      // bqkv f32 [6][384]
#define OFF_WOH  1188864u      // Wo hi [6][128][128] bf16 ([j][d])
#define OFF_WOL  1385472u
#define OFF_W1H  1582080u      // W1T hi [6][5][256][128] bf16
#define OFF_W1L  3548160u
#define OFF_W2H  5514240u      // W2T hi [6][5][128][256] bf16
#define OFF_W2L  7480320u

// ---------------- prep kernels ----------------
__global__ void prep_qkv_bf(const float* __restrict__ Wqkv, const float* __restrict__ bqkv,
                            unsigned short* __restrict__ Wqh, unsigned short* __restrict__ Wql,
                            float* __restrict__ bq){
  int bid = blockIdx.x; int n = bid % 384; int e = threadIdx.x;
  float sc = (n < 128) ? SCALE : 1.0f;
  float w = Wqkv[(size_t)bid*128 + e] * sc;
  unsigned short h = f2bf(w), l = f2bf(w - bf2f(h));
  Wqh[(size_t)bid*128 + e] = h; Wql[(size_t)bid*128 + e] = l;
  if (e == 0) bq[bid] = bqkv[bid] * sc;
}

__global__ void prep_wo_bf(const float* __restrict__ Wo,
                           unsigned short* __restrict__ Woh, unsigned short* __restrict__ Wol){
  int idx = blockIdx.x*blockDim.x + threadIdx.x;
  if (idx >= 6*128*128) return;
  float w = Wo[idx];
  unsigned short h = f2bf(w), l = f2bf(w - bf2f(h));
  Woh[idx] = h; Wol[idx] = l;
}

__global__ void prep_moe(const float* __restrict__ W1, const float* __restrict__ W2,
                         unsigned short* __restrict__ W1h, unsigned short* __restrict__ W1l,
                         unsigned short* __restrict__ W2h, unsigned short* __restrict__ W2l){
  const int Ntot = 6*5*128*256;
  for (int idx = blockIdx.x*blockDim.x + threadIdx.x; idx < Ntot; idx += gridDim.x*blockDim.x){
    int lx = idx / 32768; int rem = idx & 32767; int e = rem >> 8; int f = rem & 255;
    float w = W1[idx];
    unsigned short h = f2bf(w); unsigned short l = f2bf(w - bf2f(h));
    size_t o1 = (size_t)(lx*256+f)*128 + e;
    W1h[o1] = h; W1l[o1] = l;
    int f2 = (idx >> 7) & 255; int e2 = idx & 127;
    float w2 = W2[idx];
    unsigned short h2 = f2bf(w2); unsigned short l2 = f2bf(w2 - bf2f(h2));
    size_t o2 = (size_t)(lx*128+e2)*256 + f2;
    W2h[o2] = h2; W2l[o2] = l2;
  }
}

// ---------------- main kernel ----------------
struct Params {
  const int*   x_cat;
  const float* x_num;
  const float* x_eng;
  const float* emb;
  const float* emb_bias;
  const float* emb_eng;
  const float* emb_bias_eng;
  const float* ln0w; const float* ln0b;
  const float* ln1w; const float* ln1b;
  const float* ln2w; const float* ln2b;
  const float* bo;
  const float* Wg;   const float* bg;
  const float* b1;   const float* b2;
  const unsigned short* Wqh; const unsigned short* Wql; const float* bq;
  const unsigned short* Woh; const unsigned short* Wol;
  const unsigned short* W1h; const unsigned short* W1l;
  const unsigned short* W2h; const unsigned short* W2l;
  float* out;
};

__device__ __forceinline__ void ln_stats(const float* xs, float* s_m, float* s_r, int tid){
  if (tid < NTOK){
    const float* row = xs + tid*LDX;
    float s0=0,s1=0,s2=0,s3=0;
    for (int e=0;e<EDIM;e+=4){ s0+=row[e]; s1+=row[e+1]; s2+=row[e+2]; s3+=row[e+3]; }
    float m = (s0+s1+s2+s3)*(1.0f/EDIM);
    float v0=0,v1=0,v2=0,v3=0;
    for (int e=0;e<EDIM;e+=4){
      float d0=row[e]-m,d1=row[e+1]-m,d2=row[e+2]-m,d3=row[e+3]-m;
      v0+=d0*d0; v1+=d1*d1; v2+=d2*d2; v3+=d3*d3;
    }
    s_m[tid]=m; s_r[tid]=1.0f/sqrtf((v0+v1+v2+v3)*(1.0f/EDIM)+LN_EPS);
  }
}

// 512-thread staging of a 32-row LN'd tile, hi/lo bf16, 8 elems/thread
__device__ __forceinline__ void stage_ht(const float* xs, const float* s_m, const float* s_r,
                                         unsigned short* HTh, unsigned short* HTl,
                                         const float* lw, const float* lb, int t0, int tid){
  int row = tid >> 4;            // 0..31
  int c8  = (tid & 15) << 3;     // 0..120
  int t = t0 + row;
  union { unsigned short u[8]; u16x8 v; } hu, lu;
  if (t < NTOK){
    float m = s_m[t], r = s_r[t];
    const float* xr = &xs[t*LDX + c8];
    float4 a = *(const float4*)xr, b4 = *(const float4*)(xr+4);
    float4 w0 = *(const float4*)(lw + c8), w1 = *(const float4*)(lw + c8 + 4);
    float4 q0 = *(const float4*)(lb + c8), q1 = *(const float4*)(lb + c8 + 4);
    float vv[8] = {(a.x-m)*r*w0.x+q0.x,(a.y-m)*r*w0.y+q0.y,(a.z-m)*r*w0.z+q0.z,(a.w-m)*r*w0.w+q0.w,
                   (b4.x-m)*r*w1.x+q1.x,(b4.y-m)*r*w1.y+q1.y,(b4.z-m)*r*w1.z+q1.z,(b4.w-m)*r*w1.w+q1.w};
#pragma unroll
    for (int j2=0;j2<8;++j2){ unsigned short hb=f2bf(vv[j2]); hu.u[j2]=hb; lu.u[j2]=f2bf(vv[j2]-bf2f(hb)); }
  } else {
#pragma unroll
    for (int j2=0;j2<8;++j2){ hu.u[j2]=0; lu.u[j2]=0; }
  }
  *(u16x8*)(HTh + row*136 + c8) = hu.v;
  *(u16x8*)(HTl + row*136 + c8) = lu.v;
}

__global__ __launch_bounds__(512) __attribute__((amdgpu_waves_per_eu(2,2)))
void fam_fwd(Params p){
  __shared__ float xs[NTOK*LDX];          // 106,128 B
  __shared__ float s_m[NTOK], s_r[NTOK];  // 1,608 B
  __shared__ __align__(16) char scb[55296];

  const int b = blockIdx.x, tid = threadIdx.x;
  const int lane = tid & 63, wv = tid >> 6;   // wv 0..7

  // ---- Phase 0: embeddings ----
  {
    const int e = tid & 127, tl = tid >> 7;
    for (int t = tl; t < NTOK; t += 4){
      float v;
      if (t < NCAT){
        int idx = p.x_cat[b*(SEQL*NCAT) + (SEQL-1)*NCAT + t];
        v = p.emb[idx*EDIM+e] + p.emb_bias[t*EDIM+e];
      } else if (t < NCAT+NNUM){
        int j = t - NCAT;
        float nv = p.x_num[b*(SEQL*NNUM)+(SEQL-1)*NNUM+j];
        v = p.emb[(NEMB-NNUM+1+j)*EDIM+e]*nv + p.emb_bias[(NCAT+j)*EDIM+e];
      } else if (t < NCAT+NNUM+NENG){
        int j = t - (NCAT+NNUM);
        float ev = p.x_eng[b*NENG+j];
        v = p.emb_eng[j*EDIM+e]*ev + p.emb_bias_eng[j*EDIM+e];
      } else v = 0.f;
      xs[t*LDX+e] = v;
    }
  }
  __syncthreads();
  ln_stats(xs, s_m, s_r, tid);
  __syncthreads();
  {
    const int e = tid & 127, tl = tid >> 7;
    for (int t = tl; t < NTOK; t += 4){
      float m = s_m[t], r = s_r[t];
      xs[t*LDX+e] = (xs[t*LDX+e]-m)*r*p.ln0w[e] + p.ln0b[e];
    }
  }
  __syncthreads();

  // ---- attn LDS pointers ----
  unsigned short* Kh  = (unsigned short*)scb;                    // [224][40]
  unsigned short* Vt  = (unsigned short*)(scb + 17920);          // [32][232]
  unsigned short* HTh = (unsigned short*)(scb + 32768);          // [32][136]
  unsigned short* HTl = (unsigned short*)(scb + 32768 + 8704);   // [32][136]
  unsigned short* Sb  = (unsigned short*)(scb + 32768);          // [32][232] (aliases HT)
  unsigned short* Ob  = (unsigned short*)(scb + 32768 + 14848);  // [32][40]
  unsigned short* Qmh = (unsigned short*)(scb + 50176);          // [32][40]
  unsigned short* Qml = (unsigned short*)(scb + 52736);          // [32][40]
  float* red  = (float*)(scb + 52736);                           // [8][33] (aliases Qml)
  float* red2 = (float*)(scb + 50176);                           // [8][33] (aliases Qmh)
  // ---- moe LDS pointers ----
  unsigned short* Ahi = (unsigned short*)scb;                    // 8 KB
  unsigned short* Alo = (unsigned short*)(scb + 8192);           // 8 KB
  unsigned short* H0  = (unsigned short*)(scb + 16384);          // 16 KB
  unsigned short* H1  = (unsigned short*)(scb + 32768);          // 16 KB
  float*          gateb = (float*)(scb + 49152);                 // [201][5]

  for (int li = 0; li < NLAY; ++li){
    const float* ln1w = p.ln1w + li*EDIM;
    const float* ln1b = p.ln1b + li*EDIM;
    const float* ln2w = p.ln2w + li*EDIM;
    const float* ln2b = p.ln2b + li*EDIM;
    const float* bo   = p.bo + li*EDIM;
    const float* Wg   = p.Wg + li*EDIM*NEXP;
    const float* bg   = p.bg + li*NEXP;
    const float* b1g  = p.b1 + li*NEXP*FFD;
    const float* b2g  = p.b2 + li*NEXP*EDIM;

    ln_stats(xs, s_m, s_r, tid);   // ln1
    __syncthreads();

    f32x4 accW[7][2];              // Wo-folded attention delta
#pragma unroll
    for (int mt=0; mt<7; ++mt){ accW[mt][0]=(f32x4){0,0,0,0}; accW[mt][1]=(f32x4){0,0,0,0}; }

    const int mfw = wv & 1;
    const int ngw = wv >> 1;       // 0..3

    for (int h = 0; h < NHEAD; ++h){
      // ======== pass 1: K and V (all 8 waves) ========
      {
        int sel = ngw;
        int nrow = ((sel < 2) ? (128 + h*HD + sel*16) : (256 + h*HD + (sel-2)*16)) + (lane & 15);
        const unsigned short* Bh = p.Wqh + ((size_t)li*384 + nrow)*128 + 8*(lane>>4);
        const unsigned short* Bl = p.Wql + ((size_t)li*384 + nrow)*128 + 8*(lane>>4);
        bfrag wbh[4], wbl[4];
#pragma unroll
        for (int kf=0; kf<4; ++kf){ wbh[kf] = *(const bfrag*)(Bh + kf*32); wbl[kf] = *(const bfrag*)(Bl + kf*32); }
        float bias1 = p.bq[li*384 + nrow];

        for (int mt=0; mt<7; ++mt){
          stage_ht(xs, s_m, s_r, HTh, HTl, ln1w, ln1b, mt*32, tid);
          __syncthreads();
          {
            f32x4 aA = (f32x4){0,0,0,0}, aB = (f32x4){0,0,0,0};
#pragma unroll
            for (int kf=0; kf<4; ++kf){
              bfrag ah = *(const bfrag*)(HTh + (mfw*16 + (lane&15))*136 + kf*32 + 8*(lane>>4));
              bfrag av = *(const bfrag*)(HTl + (mfw*16 + (lane&15))*136 + kf*32 + 8*(lane>>4));
              if (kf & 1){
                aB = __builtin_amdgcn_mfma_f32_16x16x32_bf16(ah, wbh[kf], aB, 0,0,0);
                aB = __builtin_amdgcn_mfma_f32_16x16x32_bf16(ah, wbl[kf], aB, 0,0,0);
                aB = __builtin_amdgcn_mfma_f32_16x16x32_bf16(av, wbh[kf], aB, 0,0,0);
              } else {
                aA = __builtin_amdgcn_mfma_f32_16x16x32_bf16(ah, wbh[kf], aA, 0,0,0);
                aA = __builtin_amdgcn_mfma_f32_16x16x32_bf16(ah, wbl[kf], aA, 0,0,0);
                aA = __builtin_amdgcn_mfma_f32_16x16x32_bf16(av, wbh[kf], aA, 0,0,0);
              }
            }
            f32x4 acc = aA + aB;
            int col = lane & 15;
            if (sel < 2){
              int d = sel*16 + col;
#pragma unroll
              for (int reg=0; reg<4; ++reg){
                int tok = mt*32 + mfw*16 + 4*(lane>>4) + reg;
                Kh[tok*40 + d] = f2bf(acc[reg] + bias1);
              }
            } else {
              int d = (sel-2)*16 + col;
              int tokb = mt*32 + mfw*16 + 4*(lane>>4);
              u16x4 pk;
#pragma unroll
              for (int reg=0; reg<4; ++reg) pk[reg] = f2bf(acc[reg] + bias1);
              *(u16x4*)(Vt + d*232 + tokb) = pk;
            }
          }
          __syncthreads();
        }
      }

      // ======== pass 2 ========
      bfrag wobh[2], wobl[2];
#pragma unroll
      for (int i=0;i<2;++i){
        int j = (ngw + 4*i)*16 + (lane&15);
        const unsigned short* wb = p.Woh + ((size_t)li*128 + j)*128 + h*HD + 8*(lane>>4);
        const unsigned short* wl = p.Wol + ((size_t)li*128 + j)*128 + h*HD + 8*(lane>>4);
        wobh[i] = *(const bfrag*)wb; wobl[i] = *(const bfrag*)wl;
      }

#pragma unroll
      for (int mt=0; mt<7; ++mt){
        stage_ht(xs, s_m, s_r, HTh, HTl, ln1w, ln1b, mt*32, tid);
        __syncthreads();

        // Q-GEMM (waves 0-3, one per SIMD)
        if (wv < 4){
          int mf2 = wv & 1, nf = wv >> 1;
          int nrow = h*HD + nf*16 + (lane & 15);
          const unsigned short* Bh = p.Wqh + ((size_t)li*384 + nrow)*128 + 8*(lane>>4);
          const unsigned short* Bl = p.Wql + ((size_t)li*384 + nrow)*128 + 8*(lane>>4);
          f32x4 aA = (f32x4){0,0,0,0}, aB = (f32x4){0,0,0,0};
#pragma unroll
          for (int kf=0; kf<4; ++kf){
            bfrag ah = *(const bfrag*)(HTh + (mf2*16 + (lane&15))*136 + kf*32 + 8*(lane>>4));
            bfrag av = *(const bfrag*)(HTl + (mf2*16 + (lane&15))*136 + kf*32 + 8*(lane>>4));
            bfrag bh = *(const bfrag*)(Bh + kf*32);
            bfrag bl = *(const bfrag*)(Bl + kf*32);
            if (kf & 1){
              aB = __builtin_amdgcn_mfma_f32_16x16x32_bf16(ah, bh, aB, 0,0,0);
              aB = __builtin_amdgcn_mfma_f32_16x16x32_bf16(ah, bl, aB, 0,0,0);
              aB = __builtin_amdgcn_mfma_f32_16x16x32_bf16(av, bh, aB, 0,0,0);
            } else {
              aA = __builtin_amdgcn_mfma_f32_16x16x32_bf16(ah, bh, aA, 0,0,0);
              aA = __builtin_amdgcn_mfma_f32_16x16x32_bf16(ah, bl, aA, 0,0,0);
              aA = __builtin_amdgcn_mfma_f32_16x16x32_bf16(av, bh, aA, 0,0,0);
            }
          }
          f32x4 acc = aA + aB;
          float bias = p.bq[li*384 + h*HD + nf*16 + (lane&15)];
          int d = nf*16 + (lane & 15);
#pragma unroll
          for (int reg=0; reg<4; ++reg){
            float v = acc[reg] + bias;
            unsigned short hb = f2bf(v);
            int qrow = mf2*16 + 4*(lane>>4) + reg;
            Qmh[qrow*40 + d] = hb;
            Qml[qrow*40 + d] = f2bf(v - bf2f(hb));
          }
        }
        __syncthreads();

        // scores + per-wave max partials -> red
        {
          bfrag qh = *(const bfrag*)(Qmh + (mfw*16 + (lane&15))*40 + 8*(lane>>4));
          bfrag ql = *(const bfrag*)(Qml + (mfw*16 + (lane&15))*40 + 8*(lane>>4));
          float pmax = -INFINITY;
          for (int nf = ngw; nf < 14; nf += 4){
            bfrag kb = *(const bfrag*)(Kh + (nf*16 + (lane&15))*40 + 8*(lane>>4));
            f32x4 s = (f32x4){0,0,0,0};
            s = __builtin_amdgcn_mfma_f32_16x16x32_bf16(qh, kb, s, 0,0,0);
            s = __builtin_amdgcn_mfma_f32_16x16x32_bf16(ql, kb, s, 0,0,0);
            int tok = nf*16 + (lane & 15);
#pragma unroll
            for (int reg=0; reg<4; ++reg){
              int q = mfw*16 + 4*(lane>>4) + reg;
              Sb[q*232 + tok] = f2bf(s[reg]);
              if (tok < NTOK) pmax = fmaxf(pmax, s[reg]);
            }
          }
          // pmax covers 4 q-rows mixed; reduce per q-row via LDS instead:
          // write per-(wave, q-set) partial: each lane's pmax covers its 4 q rows
          // → scatter max per q by writing to red with atomic-free strategy:
          // each (wave,q) partial computed by the lanes owning that q.
          // lanes (lane&15 fixed col) share q rows; do cross-lane max over cols:
          // cols live in lane&15 (16 lanes per q-quad). Use shfl reduction over 16 col-lanes:
          float m0 = pmax;
          m0 = fmaxf(m0, __shfl_xor(m0, 1));
          m0 = fmaxf(m0, __shfl_xor(m0, 2));
          m0 = fmaxf(m0, __shfl_xor(m0, 4));
          m0 = fmaxf(m0, __shfl_xor(m0, 8));
          // now lanes with same (lane>>4) hold max over their 4 q rows & this wave's tokens
          if ((lane & 15) == 0){
            int qbase = mfw*16 + 4*(lane>>4);
            // store 4 identical values? partial max is per 4-q-row GROUP (C-frag rows share pmax)
#pragma unroll
            for (int reg=0; reg<4; ++reg) red[wv*33 + qbase + reg] = m0;
          }
        }
        __syncthreads();

        // exp + per-wave sum partials -> red2 (mr reduced inline)
        {
          int q = tid & 31, kg = tid >> 5;   // kg 0..15
          float mr = red[q];
#pragma unroll
          for (int w=1; w<8; ++w) mr = fmaxf(mr, red[w*33 + q]);
          float psum = 0.f;
#pragma unroll
          for (int j2=0; j2<14; ++j2){
            int k = kg + 16*j2;
            float pe = 0.f;
            if (k < NTOK) pe = __expf(bf2f(Sb[q*232 + k]) - mr);
            psum += pe;
            if (k < 224) Sb[q*232 + k] = f2bf(pe);
          }
          psum += __shfl_xor(psum, 32);
          if (!(tid & 32)) red2[wv*33 + q] = psum;
        }
        __syncthreads();

        // PV (waves 0-3); dsum reduced inline from red2
        if (wv < 4){
          int mf2 = wv & 1, nf = wv >> 1;
          f32x4 oA = (f32x4){0,0,0,0}, oB = (f32x4){0,0,0,0};
#pragma unroll
          for (int kf=0; kf<7; ++kf){
            bfrag pa = *(const bfrag*)(Sb + (mf2*16 + (lane&15))*232 + kf*32 + 8*(lane>>4));
            bfrag vb = *(const bfrag*)(Vt + (nf*16 + (lane&15))*232 + kf*32 + 8*(lane>>4));
            if (kf & 1) oB = __builtin_amdgcn_mfma_f32_16x16x32_bf16(pa, vb, oB, 0,0,0);
            else        oA = __builtin_amdgcn_mfma_f32_16x16x32_bf16(pa, vb, oA, 0,0,0);
          }
          f32x4 o = oA + oB;
          int d = nf*16 + (lane & 15);
#pragma unroll
          for (int reg=0; reg<4; ++reg){
            int q = mf2*16 + 4*(lane>>4) + reg;
            float s = red2[q];
#pragma unroll
            for (int w=1; w<8; ++w) s += red2[w*33 + q];
            Ob[q*40 + d] = f2bf(o[reg] * (1.0f/s));
          }
        }
        __syncthreads();

        // Wo fold into accW[mt]
        {
          bfrag oa = *(const bfrag*)(Ob + (mfw*16 + (lane&15))*40 + 8*(lane>>4));
          accW[mt][0] = __builtin_amdgcn_mfma_f32_16x16x32_bf16(oa, wobh[0], accW[mt][0], 0,0,0);
          accW[mt][0] = __builtin_amdgcn_mfma_f32_16x16x32_bf16(oa, wobl[0], accW[mt][0], 0,0,0);
          accW[mt][1] = __builtin_amdgcn_mfma_f32_16x16x32_bf16(oa, wobh[1], accW[mt][1], 0,0,0);
          accW[mt][1] = __builtin_amdgcn_mfma_f32_16x16x32_bf16(oa, wobl[1], accW[mt][1], 0,0,0);
        }
        __syncthreads();
      } // mt
    } // h

    // ---- apply attention delta + bo ----
    {
#pragma unroll
      for (int i=0;i<2;++i){
        int j = (ngw + 4*i)*16 + (lane & 15);
        float boj = bo[j];
#pragma unroll
        for (int mt=0; mt<7; ++mt){
#pragma unroll
          for (int reg=0; reg<4; ++reg){
            int t = mt*32 + mfw*16 + 4*(lane>>4) + reg;
            if (t < NTOK) xs[t*LDX + j] += accW[mt][i][reg] + boj;
          }
        }
      }
    }
    __syncthreads();

    ln_stats(xs, s_m, s_r, tid);   // ln2
    __syncthreads();

    // ---- gate ----
    if (tid < NTOK){
      const float* row = xs + tid*LDX;
      float m = s_m[tid], r = s_r[tid];
      float gl[NEXP];
#pragma unroll
      for (int x=0;x<NEXP;++x) gl[x] = bg[x];
      for (int e=0;e<EDIM;++e){
        float hv = (row[e]-m)*r*ln2w[e] + ln2b[e];
#pragma unroll
        for (int x=0;x<NEXP;++x) gl[x] += hv*Wg[e*NEXP+x];
      }
      float gm = gl[0];
#pragma unroll
      for (int x=1;x<NEXP;++x) gm = fmaxf(gm, gl[x]);
      float gs = 0.f;
#pragma unroll
      for (int x=0;x<NEXP;++x){ gl[x] = __expf(gl[x]-gm); gs += gl[x]; }
      float gi = 1.0f/gs;
#pragma unroll
      for (int x=0;x<NEXP;++x) gateb[tid*NEXP+x] = gl[x]*gi;
    }
    __syncthreads();

    // ---- MoE: MFMA, 32-token tiles, H double-buffered, 1 barrier/expert ----
    for (int t0 = 0; t0 < NTOK; t0 += 32){
      // A-stage: ln2(x) split hi/lo bf16, frag-packed
      {
        int mf = tid >> 8;
        int row = (tid & 15) + 16*mf;
        int kb  = ((tid>>6)&3)*32 + 8*((tid>>4)&3);
        int t = t0 + row;
        union { unsigned short u[8]; bfrag v; } hu, lu;
        if (t < NTOK){
          float m = s_m[t], r = s_r[t];
          const float* xr = &xs[t*LDX + kb];
          float4 a = *(const float4*)xr;
          float4 bq4 = *(const float4*)(xr+4);
          float4 w0 = *(const float4*)(ln2w + kb);
          float4 w1 = *(const float4*)(ln2w + kb + 4);
          float4 bb0 = *(const float4*)(ln2b + kb);
          float4 bb1 = *(const float4*)(ln2b + kb + 4);
          float vv[8] = {(a.x-m)*r*w0.x+bb0.x, (a.y-m)*r*w0.y+bb0.y,
                         (a.z-m)*r*w0.z+bb0.z, (a.w-m)*r*w0.w+bb0.w,
                         (bq4.x-m)*r*w1.x+bb1.x, (bq4.y-m)*r*w1.y+bb1.y,
                         (bq4.z-m)*r*w1.z+bb1.z, (bq4.w-m)*r*w1.w+bb1.w};
#pragma unroll
          for (int j=0;j<8;++j){
            unsigned short hb = f2bf(vv[j]);
            hu.u[j] = hb;
            lu.u[j] = f2bf(vv[j] - bf2f(hb));
          }
        } else {
#pragma unroll
          for (int j=0;j<8;++j){ hu.u[j]=0; lu.u[j]=0; }
        }
        *(bfrag*)(Ahi + tid*8) = hu.v;
        *(bfrag*)(Alo + tid*8) = lu.v;
      }
      __syncthreads();

      f32x4 a2[2][2];
      a2[0][0]=(f32x4){0,0,0,0}; a2[0][1]=(f32x4){0,0,0,0};
      a2[1][0]=(f32x4){0,0,0,0}; a2[1][1]=(f32x4){0,0,0,0};

      for (int x = 0; x < NEXP; ++x){
        unsigned short* Hb = (x & 1) ? H1 : H0;
        const unsigned short* W1hx = p.W1h + (size_t)(li*NEXP+x)*FFD*EDIM;
        const unsigned short* W1lx = p.W1l + (size_t)(li*NEXP+x)*FFD*EDIM;
        const unsigned short* W2hx = p.W2h + (size_t)(li*NEXP+x)*EDIM*FFD;
        const unsigned short* W2lx = p.W2l + (size_t)(li*NEXP+x)*EDIM*FFD;

        // GEMM1: wave owns 32 n-cols (2 n-frags)
        f32x4 acc1[2][2];
#pragma unroll
        for (int i=0;i<2;++i){ acc1[i][0]=(f32x4){0,0,0,0}; acc1[i][1]=(f32x4){0,0,0,0}; }
        __builtin_amdgcn_s_setprio(1);
#pragma unroll
        for (int kf=0;kf<4;++kf){
          bfrag ah[2], al[2], bh[2], bl[2];
#pragma unroll
          for (int mf=0;mf<2;++mf){
            ah[mf] = *(const bfrag*)(Ahi + ((mf*4+kf)*64 + lane)*8);
            al[mf] = *(const bfrag*)(Alo + ((mf*4+kf)*64 + lane)*8);
          }
#pragma unroll
          for (int nfl=0;nfl<2;++nfl){
            size_t n = (size_t)((wv*2+nfl)*16 + (lane&15));
            size_t off = n*128 + kf*32 + 8*(lane>>4);
            bh[nfl] = *(const bfrag*)(W1hx + off);
            bl[nfl] = *(const bfrag*)(W1lx + off);
          }
#pragma unroll
          for (int mf=0;mf<2;++mf)
#pragma unroll
            for (int nfl=0;nfl<2;++nfl){
              acc1[mf][nfl] = __builtin_amdgcn_mfma_f32_16x16x32_bf16(ah[mf], bh[nfl], acc1[mf][nfl], 0,0,0);
              acc1[mf][nfl] = __builtin_amdgcn_mfma_f32_16x16x32_bf16(ah[mf], bl[nfl], acc1[mf][nfl], 0,0,0);
              acc1[mf][nfl] = __builtin_amdgcn_mfma_f32_16x16x32_bf16(al[mf], bh[nfl], acc1[mf][nfl], 0,0,0);
            }
        }
        __builtin_amdgcn_s_setprio(0);
        // epilogue: bias, relu, gate, bf16 (hi only), scatter to Hb frag layout
        {
          int c = lane & 15;
#pragma unroll
          for (int nfl=0;nfl<2;++nfl){
            int n = (wv*2+nfl)*16 + c;
            float bb = b1g[x*FFD + n];
            int lane_t_base = 16*(2*nfl + (c>>3));
            int jcol = c & 7;
#pragma unroll
            for (int mf=0;mf<2;++mf){
#pragma unroll
              for (int reg=0;reg<4;++reg){
                int msub = (lane>>4)*4 + reg;
                int t = t0 + mf*16 + msub;
                float g = (t < NTOK) ? gateb[t*NEXP+x] : 0.f;
                float v = fmaxf(acc1[mf][nfl][reg] + bb, 0.f) * g;
                int idx = ((mf*8 + wv)*64 + msub + lane_t_base)*8 + jcol;
                Hb[idx] = f2bf(v);
              }
            }
          }
        }
        __syncthreads();

        // GEMM2 from Hb: wave owns 16 n-cols; acc across experts
        __builtin_amdgcn_s_setprio(1);
#pragma unroll
        for (int kf=0;kf<8;++kf){
          bfrag hh[2];
#pragma unroll
          for (int mf=0;mf<2;++mf)
            hh[mf] = *(const bfrag*)(Hb + ((mf*8+kf)*64 + lane)*8);
          size_t off = (size_t)(wv*16 + (lane&15))*256 + kf*32 + 8*(lane>>4);
          bfrag wh = *(const bfrag*)(W2hx + off);
          bfrag wl = *(const bfrag*)(W2lx + off);
#pragma unroll
          for (int mf=0;mf<2;++mf){
            a2[mf][kf&1] = __builtin_amdgcn_mfma_f32_16x16x32_bf16(hh[mf], wh, a2[mf][kf&1], 0,0,0);
            a2[mf][kf&1] = __builtin_amdgcn_mfma_f32_16x16x32_bf16(hh[mf], wl, a2[mf][kf&1], 0,0,0);
          }
        }
        __builtin_amdgcn_s_setprio(0);
        // no barrier: next expert's GEMM1 reads Ahi/Alo (stable) and writes the OTHER H bank
      } // x

      // tile epilogue: + sum_x g*b2, RMW xs
      {
        int c = lane & 15;
        int n = wv*16 + c;
#pragma unroll
        for (int mf=0;mf<2;++mf){
#pragma unroll
          for (int reg=0;reg<4;++reg){
            int t = t0 + mf*16 + (lane>>4)*4 + reg;
            if (t < NTOK){
              float bs = 0.f;
#pragma unroll
              for (int x=0;x<NEXP;++x) bs += gateb[t*NEXP+x]*b2g[x*EDIM+n];
              xs[t*LDX+n] += a2[mf][0][reg] + a2[mf][1][reg] + bs;
            }
          }
        }
      }
      // next tile's A-stage writes Ahi/Alo per-thread (disjoint) and barriers before GEMM1
    } // tiles
    __syncthreads();
  } // layers

  if (tid < EDIM) p.out[b*EDIM + tid] = xs[200*LDX + tid];
}

extern "C" void kernel_launch(void* const* d_in, const int* in_sizes, int n_in,
                              void* d_out, int out_size, void* d_ws, size_t ws_size,
                              hipStream_t stream) {
  (void)in_sizes; (void)n_in; (void)out_size; (void)ws_size;
  char* ws = (char*)d_ws;

  const float* Wqkv = (const float*)d_in[11];
  const float* bqkv = (const float*)d_in[12];
  const float* Wo   = (const float*)d_in[13];
  const float* W1   = (const float*)d_in[19];
  const float* W2   = (const float*)d_in[21];

  hipLaunchKernelGGL(prep_qkv_bf, dim3(6*384), dim3(128), 0, stream,
                     Wqkv, bqkv,
                     (unsigned short*)(ws+OFF_WQH), (unsigned short*)(ws+OFF_WQL),
                     (float*)(ws+OFF_BQ));
  hipLaunchKernelGGL(prep_wo_bf, dim3(384), dim3(256), 0, stream, Wo,
                     (unsigned short*)(ws+OFF_WOH), (unsigned short*)(ws+OFF_WOL));
  hipLaunchKernelGGL(prep_moe, dim3(3840), dim3(256), 0, stream, W1, W2,
                     (unsigned short*)(ws+OFF_W1H), (unsigned short*)(ws+OFF_W1L),
                     (unsigned short*)(ws+OFF_W2H), (unsigned short*)(ws+OFF_W2L));

  Params p;
  p.x_cat        = (const int*)  d_in[0];
  p.x_num        = (const float*)d_in[1];
  p.x_eng        = (const float*)d_in[2];
  p.emb          = (const float*)d_in[3];
  p.emb_bias     = (const float*)d_in[4];
  p.emb_eng      = (const float*)d_in[5];
  p.emb_bias_eng = (const float*)d_in[6];
  p.ln0w = (const float*)d_in[7];  p.ln0b = (const float*)d_in[8];
  p.ln1w = (const float*)d_in[9];  p.ln1b = (const float*)d_in[10];
  p.ln2w = (const float*)d_in[15]; p.ln2b = (const float*)d_in[16];
  p.bo   = (const float*)d_in[14];
  p.Wg   = (const float*)d_in[17]; p.bg = (const float*)d_in[18];
  p.b1   = (const float*)d_in[20]; p.b2 = (const float*)d_in[22];
  p.Wqh = (const unsigned short*)(ws+OFF_WQH);
  p.Wql = (const unsigned short*)(ws+OFF_WQL);
  p.bq  = (const float*)(ws+OFF_BQ);
  p.Woh = (const unsigned short*)(ws+OFF_WOH);
  p.Wol = (const unsigned short*)(ws+OFF_WOL);
  p.W1h = (const unsigned short*)(ws+OFF_W1H);
  p.W1l = (const unsigned short*)(ws+OFF_W1L);
  p.W2h = (const unsigned short*)(ws+OFF_W2H);
  p.W2l = (const unsigned short*)(ws+OFF_W2L);
  p.out = (float*)d_out;

  hipLaunchKernelGGL(fam_fwd, dim3(NB), dim3(512), 0, stream, p);
}